// Round 12
// baseline (366.561 us; speedup 1.0000x reference)
//
#include <hip/hip_runtime.h>
#include <hip/hip_bf16.h>
#include <stdint.h>

#define B_ 4
#define T_ 2048
#define D_ 1024
#define H_ 16
#define HD_ 64

// softmax computed as 2^(s*log2e): log2(e)/8 folded into Q projection scale
#define QSCALE 0.1803368801111244f

typedef __bf16 bf16_t;
typedef __bf16 bf16x8 __attribute__((ext_vector_type(8)));
typedef __bf16 bf16x4 __attribute__((ext_vector_type(4)));
typedef float f32x4 __attribute__((ext_vector_type(4)));

__device__ __forceinline__ f32x4 mfma16(bf16x8 a, bf16x8 b, f32x4 c) {
  return __builtin_amdgcn_mfma_f32_16x16x32_bf16(a, b, c, 0, 0, 0);
}

__device__ __forceinline__ void gload_lds16(const bf16_t* g, bf16_t* l) {
  __builtin_amdgcn_global_load_lds(
      (const __attribute__((address_space(1))) unsigned int*)g,
      (__attribute__((address_space(3))) unsigned int*)l, 16, 0, 0);
}

__device__ __forceinline__ float exp2g(float x) {
  return __builtin_amdgcn_exp2f(x);
}

// ---------------------------------------------------------------------------
// convert x fp32 -> bf16 (linear)
// ---------------------------------------------------------------------------
__global__ __launch_bounds__(256) void conv_x(const float* __restrict__ x,
                                              bf16_t* __restrict__ xb) {
  size_t i = ((size_t)blockIdx.x * 256 + threadIdx.x) * 8;
  float4 a = *(const float4*)(x + i);
  float4 b = *(const float4*)(x + i + 4);
  bf16x8 v;
  v[0] = (bf16_t)a.x; v[1] = (bf16_t)a.y; v[2] = (bf16_t)a.z; v[3] = (bf16_t)a.w;
  v[4] = (bf16_t)b.x; v[5] = (bf16_t)b.y; v[6] = (bf16_t)b.z; v[7] = (bf16_t)b.w;
  *(bf16x8*)(xb + i) = v;
}

// ---------------------------------------------------------------------------
// convert + transpose W[k][n] fp32 -> Wt[n][k] bf16 (64x64 tiles via LDS)
// blockIdx.z selects which of the 3 weight matrices (one launch).
// ---------------------------------------------------------------------------
__global__ __launch_bounds__(256) void conv_wt3(
    const float* __restrict__ Wq, const float* __restrict__ Wk,
    const float* __restrict__ Wv, bf16_t* __restrict__ WtAll) {
  __shared__ float Ls[64][65];
  const int tid = threadIdx.x;
  const int z = blockIdx.z;
  const float* W = (z == 0) ? Wq : (z == 1) ? Wk : Wv;
  bf16_t* Wt = WtAll + (size_t)z * 1024 * D_;
  const int k0 = blockIdx.y * 64, n0 = blockIdx.x * 64;
  const int rr = tid >> 4, cc = (tid & 15) * 4;
#pragma unroll
  for (int it = 0; it < 4; ++it) {
    int r = rr + it * 16;
    float4 v = *(const float4*)(W + (size_t)(k0 + r) * D_ + n0 + cc);
    Ls[r][cc] = v.x; Ls[r][cc + 1] = v.y; Ls[r][cc + 2] = v.z; Ls[r][cc + 3] = v.w;
  }
  __syncthreads();
#pragma unroll
  for (int it = 0; it < 4; ++it) {
    int nl = rr + it * 16;
    bf16x4 o;
    o[0] = (bf16_t)Ls[cc][nl];     o[1] = (bf16_t)Ls[cc + 1][nl];
    o[2] = (bf16_t)Ls[cc + 2][nl]; o[3] = (bf16_t)Ls[cc + 3][nl];
    *(bf16x4*)(Wt + (size_t)(n0 + nl) * D_ + k0 + cc) = o;
  }
}

// ---------------------------------------------------------------------------
// fused QKV GEMM: A=xb[8192][1024], Bt=WtAll[3072][1024]. 128x128 tiles,
// BK=64, global_load_lds staging. 1536 blocks, mb-fastest XCD map (round-11,
// measured: fixed the L2 B-window thrash). All three outputs now NATURAL
// layout [bh][t][d] (V no longer transposed -- PV pass eliminated).
// ---------------------------------------------------------------------------
__global__ __launch_bounds__(256) void gemm_qkv(
    const bf16_t* __restrict__ A, const bf16_t* __restrict__ Bt,
    const float* __restrict__ bq, const float* __restrict__ bk,
    const float* __restrict__ bv,
    bf16_t* __restrict__ Qo, bf16_t* __restrict__ Ko, bf16_t* __restrict__ Vo)
{
  __shared__ __align__(16) bf16_t As[128 * 64];
  __shared__ __align__(16) bf16_t Bs[128 * 64];
  const int tid = threadIdx.x, lane = tid & 63, wv = tid >> 6;
  const int wr = wv >> 1, wc = wv & 1;
  const int wg = blockIdx.x;
  const int xcd = wg & 7;
  const int local = wg >> 3;                    // 0..191
  const int mb = xcd * 8 + (local & 7);         // 64 mb, 8 per XCD
  const int nb = local >> 3;                    // 0..23
  const int m0 = mb * 128, n0 = nb * 128;
  const int mode = nb >> 3;                     // 0..2
  const int lr = lane & 15, lg = lane >> 4;
  const int srow = wv * 8 + (lane >> 3);
  const int scol = (lane & 7) * 8;

  f32x4 acc[4][4] = {};

  for (int k0 = 0; k0 < D_; k0 += 64) {
    __syncthreads();
#pragma unroll
    for (int i = 0; i < 4; ++i) {
      gload_lds16(A + (size_t)(m0 + i * 32 + srow) * D_ + k0 + scol,
                  &As[(i * 32 + wv * 8) * 64]);
      gload_lds16(Bt + (size_t)(n0 + i * 32 + srow) * D_ + k0 + scol,
                  &Bs[(i * 32 + wv * 8) * 64]);
    }
    __syncthreads();

#pragma unroll
    for (int ks = 0; ks < 2; ++ks) {
      bf16x8 af[4], bfr[4];
#pragma unroll
      for (int i = 0; i < 4; ++i)
        af[i] = *(const bf16x8*)&As[(wr * 64 + i * 16 + lr) * 64 + ks * 32 + lg * 8];
#pragma unroll
      for (int j = 0; j < 4; ++j)
        bfr[j] = *(const bf16x8*)&Bs[(wc * 64 + j * 16 + lr) * 64 + ks * 32 + lg * 8];
#pragma unroll
      for (int i = 0; i < 4; ++i)
#pragma unroll
        for (int j = 0; j < 4; ++j)
          acc[i][j] = mfma16(af[i], bfr[j], acc[i][j]);
    }
  }

  bf16_t* out = (mode == 0) ? Qo : (mode == 1) ? Ko : Vo;
  const float* bias = (mode == 0) ? bq : (mode == 1) ? bk : bv;
  const float scale = (mode == 0) ? QSCALE : 1.0f;
  const int nl0 = n0 - mode * 1024;
#pragma unroll
  for (int j = 0; j < 4; ++j) {
    int n = nl0 + wc * 64 + j * 16 + lr;
    float bval = bias[n];
    int h = n >> 6, d = n & 63;
#pragma unroll
    for (int i = 0; i < 4; ++i)
#pragma unroll
      for (int r = 0; r < 4; ++r) {
        int m = m0 + wr * 64 + i * 16 + lg * 4 + r;
        int b = m >> 11, t = m & (T_ - 1);
        float val = (acc[i][j][r] + bval) * scale;
        out[(((size_t)(b * H_ + h)) * T_ + t) * HD_ + d] = (bf16_t)val;
      }
  }
}

// ---------------------------------------------------------------------------
// fallback GEMM (fp32 inputs) — natural output only
// ---------------------------------------------------------------------------
__global__ __launch_bounds__(256) void qkv_gemm_f32(
    const float* __restrict__ x, const float* __restrict__ W,
    const float* __restrict__ bias, bf16_t* __restrict__ out, float scale)
{
  __shared__ bf16_t As[128][40];
  __shared__ bf16_t Bs[128][40];
  const int tid = threadIdx.x, lane = tid & 63, wv = tid >> 6;
  const int wr = wv >> 1, wc = wv & 1;
  const int m0 = blockIdx.y * 128, n0 = blockIdx.x * 128;
  const int lr = lane & 15, lg = lane >> 4;
  f32x4 acc[4][4] = {};
  const int xr = tid >> 3, xc = tid & 7;
  const int wk = tid >> 5, wn = tid & 31;

  for (int k0 = 0; k0 < D_; k0 += 32) {
    __syncthreads();
#pragma unroll
    for (int it = 0; it < 4; ++it) {
      int r = xr + it * 32;
      float4 v = *(const float4*)(x + (size_t)(m0 + r) * D_ + k0 + xc * 4);
      bf16_t* dst = &As[r][xc * 4];
      dst[0] = (bf16_t)v.x; dst[1] = (bf16_t)v.y;
      dst[2] = (bf16_t)v.z; dst[3] = (bf16_t)v.w;
    }
#pragma unroll
    for (int it = 0; it < 4; ++it) {
      int k = wk + it * 8;
      float4 v = *(const float4*)(W + (size_t)(k0 + k) * D_ + n0 + wn * 4);
      Bs[wn * 4 + 0][k] = (bf16_t)v.x;
      Bs[wn * 4 + 1][k] = (bf16_t)v.y;
      Bs[wn * 4 + 2][k] = (bf16_t)v.z;
      Bs[wn * 4 + 3][k] = (bf16_t)v.w;
    }
    __syncthreads();
    bf16x8 af[4], bfr[4];
#pragma unroll
    for (int i = 0; i < 4; ++i) af[i]  = *(const bf16x8*)&As[wr * 64 + i * 16 + lr][lg * 8];
#pragma unroll
    for (int j = 0; j < 4; ++j) bfr[j] = *(const bf16x8*)&Bs[wc * 64 + j * 16 + lr][lg * 8];
#pragma unroll
    for (int i = 0; i < 4; ++i)
#pragma unroll
      for (int j = 0; j < 4; ++j)
        acc[i][j] = mfma16(af[i], bfr[j], acc[i][j]);
  }

#pragma unroll
  for (int j = 0; j < 4; ++j) {
    int n = n0 + wc * 64 + j * 16 + lr;
    float bval = bias[n];
    int h = n >> 6, d = n & 63;
#pragma unroll
    for (int i = 0; i < 4; ++i)
#pragma unroll
      for (int r = 0; r < 4; ++r) {
        int m = m0 + wr * 64 + i * 16 + lg * 4 + r;
        int b = m >> 11, t = m & (T_ - 1);
        float val = (acc[i][j][r] + bval) * scale;
        out[(((size_t)(b * H_ + h)) * T_ + t) * HD_ + d] = (bf16_t)val;
      }
  }
}

// ---------------------------------------------------------------------------
// attn_rowsum: Linv[bh,q] = 1 / sum_t 2^(s[q,t]).
// 1024 blocks = 8 xcd * 8 bh * 16 qc; block owns 128 q (4 waves x 32 q,
// Q held as A-fragments in registers), streams all K as B-fragments.
// D[q][t]: row q = 4*lg + r (+16*qq), col t = lr. No LDS, no barriers.
// ---------------------------------------------------------------------------
__global__ __launch_bounds__(256) void attn_rowsum(
    const bf16_t* __restrict__ Q, const bf16_t* __restrict__ K,
    float* __restrict__ Linv)
{
  const int tid = threadIdx.x, lane = tid & 63, wv = tid >> 6;
  const int lr = lane & 15, lg = lane >> 4;
  const int wg = blockIdx.x;
  const int p_ = wg >> 3;
  const int bh = (wg & 7) * 8 + (p_ >> 4);
  const int qc = p_ & 15;
  const int q0w = qc * 128 + wv * 32;

  const bf16_t* Qb = Q + (size_t)bh * T_ * HD_;
  const bf16_t* Kb = K + (size_t)bh * T_ * HD_;

  // A-fragments: lane holds Q[q0w + qq*16 + lr][ks*32 + lg*8 + j]
  bf16x8 qa[2][2];
#pragma unroll
  for (int qq = 0; qq < 2; ++qq)
#pragma unroll
    for (int ks = 0; ks < 2; ++ks)
      qa[qq][ks] = *(const bf16x8*)(Qb + (size_t)(q0w + qq * 16 + lr) * HD_ +
                                    ks * 32 + lg * 8);

  float accl[2][4] = {};

  for (int tb = 0; tb < T_; tb += 64) {
#pragma unroll
    for (int ts = 0; ts < 4; ++ts) {
      const int t16 = tb + ts * 16;
      // B-fragments: lane holds K[t16+lr][lg*8 + j] (K^T as 32d x 16t)
      bf16x8 kb0 = *(const bf16x8*)(Kb + (size_t)(t16 + lr) * HD_ + lg * 8);
      bf16x8 kb1 = *(const bf16x8*)(Kb + (size_t)(t16 + lr) * HD_ + 32 + lg * 8);
#pragma unroll
      for (int qq = 0; qq < 2; ++qq) {
        f32x4 s = {};
        __builtin_amdgcn_s_setprio(1);
        s = mfma16(qa[qq][0], kb0, s);
        s = mfma16(qa[qq][1], kb1, s);
        __builtin_amdgcn_s_setprio(0);
#pragma unroll
        for (int r = 0; r < 4; ++r)
          accl[qq][r] += exp2g(s[r]);
      }
    }
  }

  // reduce over the 16 t-columns (lr lanes)
#pragma unroll
  for (int qq = 0; qq < 2; ++qq)
#pragma unroll
    for (int r = 0; r < 4; ++r) {
      float v = accl[qq][r];
      v += __shfl_xor(v, 1); v += __shfl_xor(v, 2);
      v += __shfl_xor(v, 4); v += __shfl_xor(v, 8);
      accl[qq][r] = v;
    }
  if (lr == 0) {
#pragma unroll
    for (int qq = 0; qq < 2; ++qq)
#pragma unroll
      for (int r = 0; r < 4; ++r)
        Linv[(size_t)bh * T_ + q0w + qq * 16 + lg * 4 + r] =
            1.f / accl[qq][r];
  }
}

// ---------------------------------------------------------------------------
// attn_colsum: colsum[b,t] += sum_q 2^s * Linv[q] (atomic across heads).
// 1024 blocks = 64 bh x 8 tc x 2 q-splits. K rows in registers. No LDS.
// ---------------------------------------------------------------------------
__global__ __launch_bounds__(256) void attn_colsum(
    const bf16_t* __restrict__ Q, const bf16_t* __restrict__ K,
    const float* __restrict__ Linv, float* __restrict__ colsum)
{
  const int tid = threadIdx.x, lane = tid & 63, wv = tid >> 6;
  const int lr = lane & 15, lg = lane >> 4;
  const int wg = blockIdx.x;
  const int p_ = wg >> 3;
  const int bh = (wg & 7) * 8 + (p_ >> 4);
  const int rem = p_ & 15;
  const int tc = rem >> 1;
  const int qs = rem & 1;
  const int b = bh >> 4;
  const int t0w = tc * 256 + wv * 64;

  const bf16_t* Qb = Q + (size_t)bh * T_ * HD_;
  const bf16_t* Kb = K + (size_t)bh * T_ * HD_;
  const float* Lb = Linv + (size_t)bh * T_;

  bf16x8 kf[4][2];
#pragma unroll
  for (int tt = 0; tt < 4; ++tt)
#pragma unroll
    for (int ks = 0; ks < 2; ++ks)
      kf[tt][ks] = *(const bf16x8*)(Kb + (size_t)(t0w + tt * 16 + lr) * HD_ +
                                    ks * 32 + lg * 8);

  float acc[4][4] = {};   // [tt][r] : t = t0w + tt*16 + 4*lg + r

  const int qlo = qs * (T_ / 2), qhi = qlo + T_ / 2;
  for (int qb = qlo; qb < qhi; qb += 64) {
#pragma unroll
    for (int qt = 0; qt < 4; ++qt) {
      const int q = qb + qt * 16 + lr;
      bf16x8 qv0 = *(const bf16x8*)(Qb + (size_t)q * HD_ + lg * 8);
      bf16x8 qv1 = *(const bf16x8*)(Qb + (size_t)q * HD_ + 32 + lg * 8);
      const float lv = Lb[q];
#pragma unroll
      for (int tt = 0; tt < 4; ++tt) {
        f32x4 s = {};
        __builtin_amdgcn_s_setprio(1);
        s = mfma16(kf[tt][0], qv0, s);
        s = mfma16(kf[tt][1], qv1, s);
        __builtin_amdgcn_s_setprio(0);
#pragma unroll
        for (int r = 0; r < 4; ++r)
          acc[tt][r] = fmaf(exp2g(s[r]), lv, acc[tt][r]);
      }
    }
  }

#pragma unroll
  for (int tt = 0; tt < 4; ++tt)
#pragma unroll
    for (int r = 0; r < 4; ++r) {
      float v = acc[tt][r];
      v += __shfl_xor(v, 1); v += __shfl_xor(v, 2);
      v += __shfl_xor(v, 4); v += __shfl_xor(v, 8);
      acc[tt][r] = v;
    }
  if (lr == 0) {
#pragma unroll
    for (int tt = 0; tt < 4; ++tt)
#pragma unroll
      for (int r = 0; r < 4; ++r)
        atomicAdd(&colsum[b * T_ + t0w + tt * 16 + lg * 4 + r], acc[tt][r]);
  }
}

// ---------------------------------------------------------------------------
// attn_w2: w2[bh,k] += sum_t pw[b,t] * 2^(s[t,k]) * Linv[bh,t], where
// pw[t] = colsum[b,t]/32768. Identical structure to attn_colsum with the
// per-row weight changed; output per-head (atomic over the 2 q-splits).
// ---------------------------------------------------------------------------
__global__ __launch_bounds__(256) void attn_w2(
    const bf16_t* __restrict__ Q, const bf16_t* __restrict__ K,
    const float* __restrict__ Linv, const float* __restrict__ CS,
    float* __restrict__ w2)
{
  const int tid = threadIdx.x, lane = tid & 63, wv = tid >> 6;
  const int lr = lane & 15, lg = lane >> 4;
  const int wg = blockIdx.x;
  const int p_ = wg >> 3;
  const int bh = (wg & 7) * 8 + (p_ >> 4);
  const int rem = p_ & 15;
  const int tc = rem >> 1;
  const int qs = rem & 1;
  const int b = bh >> 4;
  const int t0w = tc * 256 + wv * 64;

  const bf16_t* Qb = Q + (size_t)bh * T_ * HD_;
  const bf16_t* Kb = K + (size_t)bh * T_ * HD_;
  const float* Lb = Linv + (size_t)bh * T_;
  const float* Cb = CS + (size_t)b * T_;

  bf16x8 kf[4][2];
#pragma unroll
  for (int tt = 0; tt < 4; ++tt)
#pragma unroll
    for (int ks = 0; ks < 2; ++ks)
      kf[tt][ks] = *(const bf16x8*)(Kb + (size_t)(t0w + tt * 16 + lr) * HD_ +
                                    ks * 32 + lg * 8);

  float acc[4][4] = {};

  const int qlo = qs * (T_ / 2), qhi = qlo + T_ / 2;
  for (int qb = qlo; qb < qhi; qb += 64) {
#pragma unroll
    for (int qt = 0; qt < 4; ++qt) {
      const int q = qb + qt * 16 + lr;
      bf16x8 qv0 = *(const bf16x8*)(Qb + (size_t)q * HD_ + lg * 8);
      bf16x8 qv1 = *(const bf16x8*)(Qb + (size_t)q * HD_ + 32 + lg * 8);
      const float lv = Cb[q] * Lb[q] * (1.f / 32768.f);
#pragma unroll
      for (int tt = 0; tt < 4; ++tt) {
        f32x4 s = {};
        __builtin_amdgcn_s_setprio(1);
        s = mfma16(kf[tt][0], qv0, s);
        s = mfma16(kf[tt][1], qv1, s);
        __builtin_amdgcn_s_setprio(0);
#pragma unroll
        for (int r = 0; r < 4; ++r)
          acc[tt][r] = fmaf(exp2g(s[r]), lv, acc[tt][r]);
      }
    }
  }

#pragma unroll
  for (int tt = 0; tt < 4; ++tt)
#pragma unroll
    for (int r = 0; r < 4; ++r) {
      float v = acc[tt][r];
      v += __shfl_xor(v, 1); v += __shfl_xor(v, 2);
      v += __shfl_xor(v, 4); v += __shfl_xor(v, 8);
      acc[tt][r] = v;
    }
  if (lr == 0) {
#pragma unroll
    for (int tt = 0; tt < 4; ++tt)
#pragma unroll
      for (int r = 0; r < 4; ++r)
        atomicAdd(&w2[(size_t)bh * T_ + t0w + tt * 16 + lg * 4 + r],
                  acc[tt][r]);
  }
}

// ---------------------------------------------------------------------------
// pool_wv: pre[b, h*64+d] += sum_{s in chunk} w2[bh,s] * V[bh,s,d]
// (V natural layout). 512 blocks = 64 bh x 8 s-chunks; PRE zeroed beforehand.
// ---------------------------------------------------------------------------
__global__ __launch_bounds__(256) void pool_wv(
    const bf16_t* __restrict__ V, const float* __restrict__ W2,
    float* __restrict__ pre)
{
  __shared__ float sm[256];
  const int wg = blockIdx.x;
  const int bh = wg >> 3, sc = wg & 7;
  const int b = bh >> 4, h = bh & 15;
  const int tid = threadIdx.x, d = tid & 63, tg = tid >> 6;
  const bf16_t* Vb = V + (size_t)bh * T_ * HD_ + (size_t)sc * 256 * HD_;
  const float* wb = W2 + (size_t)bh * T_ + sc * 256;
  float acc = 0.f;
  for (int s = tg; s < 256; s += 4)
    acc += wb[s] * (float)Vb[(size_t)s * HD_ + d];
  sm[tid] = acc;
  __syncthreads();
  if (tid < 64) {
    float s = sm[tid] + sm[tid + 64] + sm[tid + 128] + sm[tid + 192];
    atomicAdd(&pre[b * D_ + h * 64 + tid], s);
  }
}

// ---------------------------------------------------------------------------
// out_acc: out[b,d] += sum_{k in chunk} pre[b,k]*Wo[k,d]  (+bo[d] on chunk 0)
// d_out memset to 0 beforehand. 128 blocks = 4 d-chunks x 32 k-chunks.
// ---------------------------------------------------------------------------
__global__ __launch_bounds__(256) void out_acc(
    const float* __restrict__ pre, const float* __restrict__ Wo,
    const float* __restrict__ bo, float* __restrict__ out)
{
  const int dc = blockIdx.x & 3, kb = blockIdx.x >> 2;
  const int d = dc * 256 + threadIdx.x;
  const int k0 = kb * 32;
  float acc0 = 0.f, acc1 = 0.f, acc2 = 0.f, acc3 = 0.f;
#pragma unroll
  for (int kk = 0; kk < 32; ++kk) {
    const int k = k0 + kk;
    const float w = Wo[(size_t)k * D_ + d];
    acc0 = fmaf(pre[k],            w, acc0);
    acc1 = fmaf(pre[D_ + k],       w, acc1);
    acc2 = fmaf(pre[2 * D_ + k],   w, acc2);
    acc3 = fmaf(pre[3 * D_ + k],   w, acc3);
  }
  if (kb == 0) {
    const float bd = bo[d];
    acc0 += bd; acc1 += bd; acc2 += bd; acc3 += bd;
  }
  atomicAdd(&out[d],           acc0);
  atomicAdd(&out[D_ + d],      acc1);
  atomicAdd(&out[2 * D_ + d],  acc2);
  atomicAdd(&out[3 * D_ + d],  acc3);
}

// ---------------------------------------------------------------------------
extern "C" void kernel_launch(void* const* d_in, const int* in_sizes, int n_in,
                              void* d_out, int out_size, void* d_ws, size_t ws_size,
                              hipStream_t stream)
{
  (void)in_sizes; (void)n_in; (void)out_size;
  const float* x  = (const float*)d_in[0];
  const float* Wq = (const float*)d_in[1];
  const float* bq = (const float*)d_in[2];
  const float* Wk = (const float*)d_in[3];
  const float* bk = (const float*)d_in[4];
  const float* Wv = (const float*)d_in[5];
  const float* bv = (const float*)d_in[6];
  const float* Wo = (const float*)d_in[7];
  const float* bo = (const float*)d_in[8];
  float* out = (float*)d_out;

  char* ws = (char*)d_ws;
  const size_t MB = 1ull << 20;
  const size_t KB = 1024;
  bf16_t* Qw = (bf16_t*)(ws);
  bf16_t* Kw = (bf16_t*)(ws + 16 * MB);
  bf16_t* Vw = (bf16_t*)(ws + 32 * MB);
  bf16_t* XB = (bf16_t*)(ws + 48 * MB);    // xb (bf16 input)
  const size_t need_fast = 72 * MB;
  const bool fast = ws_size >= need_fast;

  // scalars region: LV | CS | PRE | W2 (CS..W2 zeroed in one memset)
  size_t soff = fast ? 70 * MB : 64 * MB;
  float* LV  = (float*)(ws + soff);                    // 512 KB
  float* CS  = (float*)(ws + soff + 512 * KB);         // 32 KB
  float* PRE = (float*)(ws + soff + 544 * KB);         // 16 KB
  float* W2  = (float*)(ws + soff + 560 * KB);         // 512 KB
  dim3 blk(256, 1, 1);

  if (fast) {
    bf16_t* WtAll = (bf16_t*)(ws + 64 * MB);  // [3072][1024] bf16 = 6 MB
    conv_x<<<dim3((B_ * T_ * D_) / (256 * 8), 1, 1), blk, 0, stream>>>(x, XB);
    conv_wt3<<<dim3(16, 16, 3), blk, 0, stream>>>(Wq, Wk, Wv, WtAll);
    gemm_qkv<<<dim3(1536, 1, 1), blk, 0, stream>>>(XB, WtAll, bq, bk, bv,
                                                   Qw, Kw, Vw);
  } else {
    qkv_gemm_f32<<<dim3(8, 64, 1), blk, 0, stream>>>(x, Wq, bq, Qw, QSCALE);
    qkv_gemm_f32<<<dim3(8, 64, 1), blk, 0, stream>>>(x, Wk, bk, Kw, 1.0f);
    qkv_gemm_f32<<<dim3(8, 64, 1), blk, 0, stream>>>(x, Wv, bv, Vw, 1.0f);
  }

  // zero CS + PRE + W2 (contiguous) and out
  hipMemsetAsync(CS, 0, 560 * KB - 512 * KB + 512 * KB, stream);
  hipMemsetAsync(out, 0, (size_t)B_ * D_ * sizeof(float), stream);

  attn_rowsum<<<dim3(1024, 1, 1), blk, 0, stream>>>(Qw, Kw, LV);
  attn_colsum<<<dim3(1024, 1, 1), blk, 0, stream>>>(Qw, Kw, LV, CS);
  attn_w2<<<dim3(1024, 1, 1), blk, 0, stream>>>(Qw, Kw, LV, CS, W2);
  pool_wv<<<dim3(512, 1, 1), blk, 0, stream>>>(Vw, W2, PRE);
  out_acc<<<dim3(128, 1, 1), blk, 0, stream>>>(PRE, Wo, bo, out);
}

// Round 13
// 308.884 us; speedup vs baseline: 1.1867x; 1.1867x over previous
//
#include <hip/hip_runtime.h>
#include <hip/hip_bf16.h>
#include <stdint.h>

#define B_ 4
#define T_ 2048
#define D_ 1024
#define H_ 16
#define HD_ 64

// softmax computed as 2^(s*log2e): log2(e)/8 folded into Q projection scale
#define QSCALE 0.1803368801111244f

typedef __bf16 bf16_t;
typedef __bf16 bf16x8 __attribute__((ext_vector_type(8)));
typedef __bf16 bf16x4 __attribute__((ext_vector_type(4)));
typedef float f32x4 __attribute__((ext_vector_type(4)));

__device__ __forceinline__ f32x4 mfma16(bf16x8 a, bf16x8 b, f32x4 c) {
  return __builtin_amdgcn_mfma_f32_16x16x32_bf16(a, b, c, 0, 0, 0);
}

__device__ __forceinline__ void gload_lds16(const bf16_t* g, bf16_t* l) {
  __builtin_amdgcn_global_load_lds(
      (const __attribute__((address_space(1))) unsigned int*)g,
      (__attribute__((address_space(3))) unsigned int*)l, 16, 0, 0);
}

__device__ __forceinline__ float exp2g(float x) {
  return __builtin_amdgcn_exp2f(x);
}

// ---------------------------------------------------------------------------
// convert x fp32 -> bf16 (linear)
// ---------------------------------------------------------------------------
__global__ __launch_bounds__(256) void conv_x(const float* __restrict__ x,
                                              bf16_t* __restrict__ xb) {
  size_t i = ((size_t)blockIdx.x * 256 + threadIdx.x) * 8;
  float4 a = *(const float4*)(x + i);
  float4 b = *(const float4*)(x + i + 4);
  bf16x8 v;
  v[0] = (bf16_t)a.x; v[1] = (bf16_t)a.y; v[2] = (bf16_t)a.z; v[3] = (bf16_t)a.w;
  v[4] = (bf16_t)b.x; v[5] = (bf16_t)b.y; v[6] = (bf16_t)b.z; v[7] = (bf16_t)b.w;
  *(bf16x8*)(xb + i) = v;
}

// ---------------------------------------------------------------------------
// convert + transpose W[k][n] fp32 -> Wt[n][k] bf16 (64x64 tiles via LDS)
// ---------------------------------------------------------------------------
__global__ __launch_bounds__(256) void conv_wt3(
    const float* __restrict__ Wq, const float* __restrict__ Wk,
    const float* __restrict__ Wv, bf16_t* __restrict__ WtAll) {
  __shared__ float Ls[64][65];
  const int tid = threadIdx.x;
  const int z = blockIdx.z;
  const float* W = (z == 0) ? Wq : (z == 1) ? Wk : Wv;
  bf16_t* Wt = WtAll + (size_t)z * 1024 * D_;
  const int k0 = blockIdx.y * 64, n0 = blockIdx.x * 64;
  const int rr = tid >> 4, cc = (tid & 15) * 4;
#pragma unroll
  for (int it = 0; it < 4; ++it) {
    int r = rr + it * 16;
    float4 v = *(const float4*)(W + (size_t)(k0 + r) * D_ + n0 + cc);
    Ls[r][cc] = v.x; Ls[r][cc + 1] = v.y; Ls[r][cc + 2] = v.z; Ls[r][cc + 3] = v.w;
  }
  __syncthreads();
#pragma unroll
  for (int it = 0; it < 4; ++it) {
    int nl = rr + it * 16;
    bf16x4 o;
    o[0] = (bf16_t)Ls[cc][nl];     o[1] = (bf16_t)Ls[cc + 1][nl];
    o[2] = (bf16_t)Ls[cc + 2][nl]; o[3] = (bf16_t)Ls[cc + 3][nl];
    *(bf16x4*)(Wt + (size_t)(n0 + nl) * D_ + k0 + cc) = o;
  }
}

// ---------------------------------------------------------------------------
// fused QKV GEMM (round-11 structure + natural V): 128x128 tiles, BK=64,
// global_load_lds staging, mb-fastest XCD map.
// ---------------------------------------------------------------------------
__global__ __launch_bounds__(256) void gemm_qkv(
    const bf16_t* __restrict__ A, const bf16_t* __restrict__ Bt,
    const float* __restrict__ bq, const float* __restrict__ bk,
    const float* __restrict__ bv,
    bf16_t* __restrict__ Qo, bf16_t* __restrict__ Ko, bf16_t* __restrict__ Vo)
{
  __shared__ __align__(16) bf16_t As[128 * 64];
  __shared__ __align__(16) bf16_t Bs[128 * 64];
  const int tid = threadIdx.x, lane = tid & 63, wv = tid >> 6;
  const int wr = wv >> 1, wc = wv & 1;
  const int wg = blockIdx.x;
  const int xcd = wg & 7;
  const int local = wg >> 3;                    // 0..191
  const int mb = xcd * 8 + (local & 7);         // 64 mb, 8 per XCD
  const int nb = local >> 3;                    // 0..23
  const int m0 = mb * 128, n0 = nb * 128;
  const int mode = nb >> 3;                     // 0..2
  const int lr = lane & 15, lg = lane >> 4;
  const int srow = wv * 8 + (lane >> 3);
  const int scol = (lane & 7) * 8;

  f32x4 acc[4][4] = {};

  for (int k0 = 0; k0 < D_; k0 += 64) {
    __syncthreads();
#pragma unroll
    for (int i = 0; i < 4; ++i) {
      gload_lds16(A + (size_t)(m0 + i * 32 + srow) * D_ + k0 + scol,
                  &As[(i * 32 + wv * 8) * 64]);
      gload_lds16(Bt + (size_t)(n0 + i * 32 + srow) * D_ + k0 + scol,
                  &Bs[(i * 32 + wv * 8) * 64]);
    }
    __syncthreads();

#pragma unroll
    for (int ks = 0; ks < 2; ++ks) {
      bf16x8 af[4], bfr[4];
#pragma unroll
      for (int i = 0; i < 4; ++i)
        af[i] = *(const bf16x8*)&As[(wr * 64 + i * 16 + lr) * 64 + ks * 32 + lg * 8];
#pragma unroll
      for (int j = 0; j < 4; ++j)
        bfr[j] = *(const bf16x8*)&Bs[(wc * 64 + j * 16 + lr) * 64 + ks * 32 + lg * 8];
#pragma unroll
      for (int i = 0; i < 4; ++i)
#pragma unroll
        for (int j = 0; j < 4; ++j)
          acc[i][j] = mfma16(af[i], bfr[j], acc[i][j]);
    }
  }

  bf16_t* out = (mode == 0) ? Qo : (mode == 1) ? Ko : Vo;
  const float* bias = (mode == 0) ? bq : (mode == 1) ? bk : bv;
  const float scale = (mode == 0) ? QSCALE : 1.0f;
  const int nl0 = n0 - mode * 1024;
#pragma unroll
  for (int j = 0; j < 4; ++j) {
    int n = nl0 + wc * 64 + j * 16 + lr;
    float bval = bias[n];
    int h = n >> 6, d = n & 63;
#pragma unroll
    for (int i = 0; i < 4; ++i)
#pragma unroll
      for (int r = 0; r < 4; ++r) {
        int m = m0 + wr * 64 + i * 16 + lg * 4 + r;
        int b = m >> 11, t = m & (T_ - 1);
        float val = (acc[i][j][r] + bval) * scale;
        out[(((size_t)(b * H_ + h)) * T_ + t) * HD_ + d] = (bf16_t)val;
      }
  }
}

// ---------------------------------------------------------------------------
// fallback GEMM (fp32 inputs) — natural output only
// ---------------------------------------------------------------------------
__global__ __launch_bounds__(256) void qkv_gemm_f32(
    const float* __restrict__ x, const float* __restrict__ W,
    const float* __restrict__ bias, bf16_t* __restrict__ out, float scale)
{
  __shared__ bf16_t As[128][40];
  __shared__ bf16_t Bs[128][40];
  const int tid = threadIdx.x, lane = tid & 63, wv = tid >> 6;
  const int wr = wv >> 1, wc = wv & 1;
  const int m0 = blockIdx.y * 128, n0 = blockIdx.x * 128;
  const int lr = lane & 15, lg = lane >> 4;
  f32x4 acc[4][4] = {};
  const int xr = tid >> 3, xc = tid & 7;
  const int wk = tid >> 5, wn = tid & 31;

  for (int k0 = 0; k0 < D_; k0 += 32) {
    __syncthreads();
#pragma unroll
    for (int it = 0; it < 4; ++it) {
      int r = xr + it * 32;
      float4 v = *(const float4*)(x + (size_t)(m0 + r) * D_ + k0 + xc * 4);
      bf16_t* dst = &As[r][xc * 4];
      dst[0] = (bf16_t)v.x; dst[1] = (bf16_t)v.y;
      dst[2] = (bf16_t)v.z; dst[3] = (bf16_t)v.w;
    }
#pragma unroll
    for (int it = 0; it < 4; ++it) {
      int k = wk + it * 8;
      float4 v = *(const float4*)(W + (size_t)(k0 + k) * D_ + n0 + wn * 4);
      Bs[wn * 4 + 0][k] = (bf16_t)v.x;
      Bs[wn * 4 + 1][k] = (bf16_t)v.y;
      Bs[wn * 4 + 2][k] = (bf16_t)v.z;
      Bs[wn * 4 + 3][k] = (bf16_t)v.w;
    }
    __syncthreads();
    bf16x8 af[4], bfr[4];
#pragma unroll
    for (int i = 0; i < 4; ++i) af[i]  = *(const bf16x8*)&As[wr * 64 + i * 16 + lr][lg * 8];
#pragma unroll
    for (int j = 0; j < 4; ++j) bfr[j] = *(const bf16x8*)&Bs[wc * 64 + j * 16 + lr][lg * 8];
#pragma unroll
    for (int i = 0; i < 4; ++i)
#pragma unroll
      for (int j = 0; j < 4; ++j)
        acc[i][j] = mfma16(af[i], bfr[j], acc[i][j]);
  }

#pragma unroll
  for (int j = 0; j < 4; ++j) {
    int n = n0 + wc * 64 + j * 16 + lr;
    float bval = bias[n];
    int h = n >> 6, d = n & 63;
#pragma unroll
    for (int i = 0; i < 4; ++i)
#pragma unroll
      for (int r = 0; r < 4; ++r) {
        int m = m0 + wr * 64 + i * 16 + lg * 4 + r;
        int b = m >> 11, t = m & (T_ - 1);
        float val = (acc[i][j][r] + bval) * scale;
        out[(((size_t)(b * H_ + h)) * T_ + t) * HD_ + d] = (bf16_t)val;
      }
  }
}

// ---------------------------------------------------------------------------
// attn_rowsum v2: Lsum[bh,q] += sum_t 2^s. Wave holds 64 q as A-frags
// (4 independent MFMA chains per streamed K load), block = 256 q, 2-way
// t-split. 1024 blocks = 8 xcd * 8 bh * 8 qc * 2 th. No LDS, no barriers.
// ---------------------------------------------------------------------------
__global__ __launch_bounds__(256) void attn_rowsum(
    const bf16_t* __restrict__ Q, const bf16_t* __restrict__ K,
    float* __restrict__ Lsum)
{
  const int tid = threadIdx.x, lane = tid & 63, wv = tid >> 6;
  const int lr = lane & 15, lg = lane >> 4;
  const int wg = blockIdx.x;
  const int p_ = wg >> 3;
  const int bh = (wg & 7) * 8 + (p_ >> 4);
  const int rem = p_ & 15;
  const int qc = rem >> 1;
  const int th = rem & 1;
  const int q0w = qc * 256 + wv * 64;

  const bf16_t* Qb = Q + (size_t)bh * T_ * HD_;
  const bf16_t* Kb = K + (size_t)bh * T_ * HD_;

  // A-fragments: lane holds Q[q0w + qq*16 + lr][ks*32 + lg*8 + j]
  bf16x8 qa[4][2];
#pragma unroll
  for (int qq = 0; qq < 4; ++qq)
#pragma unroll
    for (int ks = 0; ks < 2; ++ks)
      qa[qq][ks] = *(const bf16x8*)(Qb + (size_t)(q0w + qq * 16 + lr) * HD_ +
                                    ks * 32 + lg * 8);

  float acc[4][4] = {};   // [qq][r] : q = q0w + qq*16 + 4*lg + r

  const int tlo = th * (T_ / 2), thi = tlo + T_ / 2;
  for (int tb = tlo; tb < thi; tb += 64) {
#pragma unroll
    for (int ts = 0; ts < 4; ++ts) {
      const int t16 = tb + ts * 16;
      bf16x8 kb0 = *(const bf16x8*)(Kb + (size_t)(t16 + lr) * HD_ + lg * 8);
      bf16x8 kb1 = *(const bf16x8*)(Kb + (size_t)(t16 + lr) * HD_ + 32 + lg * 8);
#pragma unroll
      for (int qq = 0; qq < 4; ++qq) {
        f32x4 s = {};
        __builtin_amdgcn_s_setprio(1);
        s = mfma16(qa[qq][0], kb0, s);
        s = mfma16(qa[qq][1], kb1, s);
        __builtin_amdgcn_s_setprio(0);
#pragma unroll
        for (int r = 0; r < 4; ++r)
          acc[qq][r] += exp2g(s[r]);
      }
    }
  }

#pragma unroll
  for (int qq = 0; qq < 4; ++qq)
#pragma unroll
    for (int r = 0; r < 4; ++r) {
      float v = acc[qq][r];
      v += __shfl_xor(v, 1); v += __shfl_xor(v, 2);
      v += __shfl_xor(v, 4); v += __shfl_xor(v, 8);
      acc[qq][r] = v;
    }
  if (lr == 0) {
#pragma unroll
    for (int qq = 0; qq < 4; ++qq)
#pragma unroll
      for (int r = 0; r < 4; ++r)
        atomicAdd(&Lsum[(size_t)bh * T_ + q0w + qq * 16 + lg * 4 + r],
                  acc[qq][r]);
  }
}

// ---------------------------------------------------------------------------
// inv_l: Lsum -> 1/Lsum in place. 131072 floats, float4 per thread.
// ---------------------------------------------------------------------------
__global__ __launch_bounds__(256) void inv_l(float* __restrict__ L) {
  size_t i = ((size_t)blockIdx.x * 256 + threadIdx.x) * 4;
  float4 v = *(float4*)(L + i);
  v.x = 1.f / v.x; v.y = 1.f / v.y; v.z = 1.f / v.z; v.w = 1.f / v.w;
  *(float4*)(L + i) = v;
}

// ---------------------------------------------------------------------------
// attn_colsum v2: colsum[b,t] += sum_q 2^s * Linv[q]. Wave holds 128 t as
// A-frags (8 chains per streamed Q load). 1024 blocks = 8 xcd * 8 bh *
// 4 tc * 4 qs. No LDS, no barriers.
// ---------------------------------------------------------------------------
__global__ __launch_bounds__(256) void attn_colsum(
    const bf16_t* __restrict__ Q, const bf16_t* __restrict__ K,
    const float* __restrict__ Linv, float* __restrict__ colsum)
{
  const int tid = threadIdx.x, lane = tid & 63, wv = tid >> 6;
  const int lr = lane & 15, lg = lane >> 4;
  const int wg = blockIdx.x;
  const int p_ = wg >> 3;
  const int bh = (wg & 7) * 8 + (p_ >> 4);
  const int rem = p_ & 15;
  const int tc = rem >> 2;
  const int qs = rem & 3;
  const int b = bh >> 4;
  const int t0w = tc * 512 + wv * 128;

  const bf16_t* Qb = Q + (size_t)bh * T_ * HD_;
  const bf16_t* Kb = K + (size_t)bh * T_ * HD_;
  const float* Lb = Linv + (size_t)bh * T_;

  bf16x8 kf[8][2];
#pragma unroll
  for (int tt = 0; tt < 8; ++tt)
#pragma unroll
    for (int ks = 0; ks < 2; ++ks)
      kf[tt][ks] = *(const bf16x8*)(Kb + (size_t)(t0w + tt * 16 + lr) * HD_ +
                                    ks * 32 + lg * 8);

  float acc[8][4] = {};   // [tt][r] : t = t0w + tt*16 + 4*lg + r

  const int qlo = qs * (T_ / 4), qhi = qlo + T_ / 4;
  for (int qb = qlo; qb < qhi; qb += 64) {
#pragma unroll
    for (int qt = 0; qt < 4; ++qt) {
      const int q = qb + qt * 16 + lr;
      bf16x8 qv0 = *(const bf16x8*)(Qb + (size_t)q * HD_ + lg * 8);
      bf16x8 qv1 = *(const bf16x8*)(Qb + (size_t)q * HD_ + 32 + lg * 8);
      const float lv = Lb[q];
#pragma unroll
      for (int tt = 0; tt < 8; ++tt) {
        f32x4 s = {};
        __builtin_amdgcn_s_setprio(1);
        s = mfma16(kf[tt][0], qv0, s);
        s = mfma16(kf[tt][1], qv1, s);
        __builtin_amdgcn_s_setprio(0);
#pragma unroll
        for (int r = 0; r < 4; ++r)
          acc[tt][r] = fmaf(exp2g(s[r]), lv, acc[tt][r]);
      }
    }
  }

#pragma unroll
  for (int tt = 0; tt < 8; ++tt)
#pragma unroll
    for (int r = 0; r < 4; ++r) {
      float v = acc[tt][r];
      v += __shfl_xor(v, 1); v += __shfl_xor(v, 2);
      v += __shfl_xor(v, 4); v += __shfl_xor(v, 8);
      acc[tt][r] = v;
    }
  if (lr == 0) {
#pragma unroll
    for (int tt = 0; tt < 8; ++tt)
#pragma unroll
      for (int r = 0; r < 4; ++r)
        atomicAdd(&colsum[b * T_ + t0w + tt * 16 + lg * 4 + r], acc[tt][r]);
  }
}

// ---------------------------------------------------------------------------
// attn_w2 v2: w2[bh,k] += sum_t (colsum[b,t]/32768) * 2^s * Linv[t].
// Same structure as attn_colsum with per-row weight changed.
// ---------------------------------------------------------------------------
__global__ __launch_bounds__(256) void attn_w2(
    const bf16_t* __restrict__ Q, const bf16_t* __restrict__ K,
    const float* __restrict__ Linv, const float* __restrict__ CS,
    float* __restrict__ w2)
{
  const int tid = threadIdx.x, lane = tid & 63, wv = tid >> 6;
  const int lr = lane & 15, lg = lane >> 4;
  const int wg = blockIdx.x;
  const int p_ = wg >> 3;
  const int bh = (wg & 7) * 8 + (p_ >> 4);
  const int rem = p_ & 15;
  const int tc = rem >> 2;
  const int qs = rem & 3;
  const int b = bh >> 4;
  const int t0w = tc * 512 + wv * 128;

  const bf16_t* Qb = Q + (size_t)bh * T_ * HD_;
  const bf16_t* Kb = K + (size_t)bh * T_ * HD_;
  const float* Lb = Linv + (size_t)bh * T_;
  const float* Cb = CS + (size_t)b * T_;

  bf16x8 kf[8][2];
#pragma unroll
  for (int tt = 0; tt < 8; ++tt)
#pragma unroll
    for (int ks = 0; ks < 2; ++ks)
      kf[tt][ks] = *(const bf16x8*)(Kb + (size_t)(t0w + tt * 16 + lr) * HD_ +
                                    ks * 32 + lg * 8);

  float acc[8][4] = {};

  const int qlo = qs * (T_ / 4), qhi = qlo + T_ / 4;
  for (int qb = qlo; qb < qhi; qb += 64) {
#pragma unroll
    for (int qt = 0; qt < 4; ++qt) {
      const int q = qb + qt * 16 + lr;
      bf16x8 qv0 = *(const bf16x8*)(Qb + (size_t)q * HD_ + lg * 8);
      bf16x8 qv1 = *(const bf16x8*)(Qb + (size_t)q * HD_ + 32 + lg * 8);
      const float lv = Cb[q] * Lb[q] * (1.f / 32768.f);
#pragma unroll
      for (int tt = 0; tt < 8; ++tt) {
        f32x4 s = {};
        __builtin_amdgcn_s_setprio(1);
        s = mfma16(kf[tt][0], qv0, s);
        s = mfma16(kf[tt][1], qv1, s);
        __builtin_amdgcn_s_setprio(0);
#pragma unroll
        for (int r = 0; r < 4; ++r)
          acc[tt][r] = fmaf(exp2g(s[r]), lv, acc[tt][r]);
      }
    }
  }

#pragma unroll
  for (int tt = 0; tt < 8; ++tt)
#pragma unroll
    for (int r = 0; r < 4; ++r) {
      float v = acc[tt][r];
      v += __shfl_xor(v, 1); v += __shfl_xor(v, 2);
      v += __shfl_xor(v, 4); v += __shfl_xor(v, 8);
      acc[tt][r] = v;
    }
  if (lr == 0) {
#pragma unroll
    for (int tt = 0; tt < 8; ++tt)
#pragma unroll
      for (int r = 0; r < 4; ++r)
        atomicAdd(&w2[(size_t)bh * T_ + t0w + tt * 16 + lg * 4 + r],
                  acc[tt][r]);
  }
}

// ---------------------------------------------------------------------------
// pool_wv: pre[b, h*64+d] += sum_{s in chunk} w2[bh,s] * V[bh,s,d]
// ---------------------------------------------------------------------------
__global__ __launch_bounds__(256) void pool_wv(
    const bf16_t* __restrict__ V, const float* __restrict__ W2,
    float* __restrict__ pre)
{
  __shared__ float sm[256];
  const int wg = blockIdx.x;
  const int bh = wg >> 3, sc = wg & 7;
  const int b = bh >> 4, h = bh & 15;
  const int tid = threadIdx.x, d = tid & 63, tg = tid >> 6;
  const bf16_t* Vb = V + (size_t)bh * T_ * HD_ + (size_t)sc * 256 * HD_;
  const float* wb = W2 + (size_t)bh * T_ + sc * 256;
  float acc = 0.f;
  for (int s = tg; s < 256; s += 4)
    acc += wb[s] * (float)Vb[(size_t)s * HD_ + d];
  sm[tid] = acc;
  __syncthreads();
  if (tid < 64) {
    float s = sm[tid] + sm[tid + 64] + sm[tid + 128] + sm[tid + 192];
    atomicAdd(&pre[b * D_ + h * 64 + tid], s);
  }
}

// ---------------------------------------------------------------------------
// out_acc: out[b,d] += sum_{k in chunk} pre[b,k]*Wo[k,d]  (+bo[d] on chunk 0)
// ---------------------------------------------------------------------------
__global__ __launch_bounds__(256) void out_acc(
    const float* __restrict__ pre, const float* __restrict__ Wo,
    const float* __restrict__ bo, float* __restrict__ out)
{
  const int dc = blockIdx.x & 3, kb = blockIdx.x >> 2;
  const int d = dc * 256 + threadIdx.x;
  const int k0 = kb * 32;
  float acc0 = 0.f, acc1 = 0.f, acc2 = 0.f, acc3 = 0.f;
#pragma unroll
  for (int kk = 0; kk < 32; ++kk) {
    const int k = k0 + kk;
    const float w = Wo[(size_t)k * D_ + d];
    acc0 = fmaf(pre[k],            w, acc0);
    acc1 = fmaf(pre[D_ + k],       w, acc1);
    acc2 = fmaf(pre[2 * D_ + k],   w, acc2);
    acc3 = fmaf(pre[3 * D_ + k],   w, acc3);
  }
  if (kb == 0) {
    const float bd = bo[d];
    acc0 += bd; acc1 += bd; acc2 += bd; acc3 += bd;
  }
  atomicAdd(&out[d],           acc0);
  atomicAdd(&out[D_ + d],      acc1);
  atomicAdd(&out[2 * D_ + d],  acc2);
  atomicAdd(&out[3 * D_ + d],  acc3);
}

// ---------------------------------------------------------------------------
extern "C" void kernel_launch(void* const* d_in, const int* in_sizes, int n_in,
                              void* d_out, int out_size, void* d_ws, size_t ws_size,
                              hipStream_t stream)
{
  (void)in_sizes; (void)n_in; (void)out_size;
  const float* x  = (const float*)d_in[0];
  const float* Wq = (const float*)d_in[1];
  const float* bq = (const float*)d_in[2];
  const float* Wk = (const float*)d_in[3];
  const float* bk = (const float*)d_in[4];
  const float* Wv = (const float*)d_in[5];
  const float* bv = (const float*)d_in[6];
  const float* Wo = (const float*)d_in[7];
  const float* bo = (const float*)d_in[8];
  float* out = (float*)d_out;

  char* ws = (char*)d_ws;
  const size_t MB = 1ull << 20;
  const size_t KB = 1024;
  bf16_t* Qw = (bf16_t*)(ws);
  bf16_t* Kw = (bf16_t*)(ws + 16 * MB);
  bf16_t* Vw = (bf16_t*)(ws + 32 * MB);
  bf16_t* XB = (bf16_t*)(ws + 48 * MB);
  const size_t need_fast = 72 * MB;
  const bool fast = ws_size >= need_fast;

  // scalars region (all zeroed in one memset): LV | CS | PRE | W2
  size_t soff = fast ? 70 * MB : 64 * MB;
  float* LV  = (float*)(ws + soff);                    // 512 KB (Lsum->Linv)
  float* CS  = (float*)(ws + soff + 512 * KB);         // 32 KB
  float* PRE = (float*)(ws + soff + 544 * KB);         // 16 KB
  float* W2  = (float*)(ws + soff + 560 * KB);         // 512 KB
  dim3 blk(256, 1, 1);

  if (fast) {
    bf16_t* WtAll = (bf16_t*)(ws + 64 * MB);  // [3072][1024] bf16 = 6 MB
    conv_x<<<dim3((B_ * T_ * D_) / (256 * 8), 1, 1), blk, 0, stream>>>(x, XB);
    conv_wt3<<<dim3(16, 16, 3), blk, 0, stream>>>(Wq, Wk, Wv, WtAll);
    gemm_qkv<<<dim3(1536, 1, 1), blk, 0, stream>>>(XB, WtAll, bq, bk, bv,
                                                   Qw, Kw, Vw);
  } else {
    qkv_gemm_f32<<<dim3(8, 64, 1), blk, 0, stream>>>(x, Wq, bq, Qw, QSCALE);
    qkv_gemm_f32<<<dim3(8, 64, 1), blk, 0, stream>>>(x, Wk, bk, Kw, 1.0f);
    qkv_gemm_f32<<<dim3(8, 64, 1), blk, 0, stream>>>(x, Wv, bv, Vw, 1.0f);
  }

  hipMemsetAsync(LV, 0, 1072 * KB, stream);
  hipMemsetAsync(out, 0, (size_t)B_ * D_ * sizeof(float), stream);

  attn_rowsum<<<dim3(1024, 1, 1), blk, 0, stream>>>(Qw, Kw, LV);
  inv_l<<<dim3((B_ * H_ * T_) / (256 * 4), 1, 1), blk, 0, stream>>>(LV);
  attn_colsum<<<dim3(1024, 1, 1), blk, 0, stream>>>(Qw, Kw, LV, CS);
  attn_w2<<<dim3(1024, 1, 1), blk, 0, stream>>>(Qw, Kw, LV, CS, W2);
  pool_wv<<<dim3(512, 1, 1), blk, 0, stream>>>(Vw, W2, PRE);
  out_acc<<<dim3(128, 1, 1), blk, 0, stream>>>(PRE, Wo, bo, out);
}

// Round 14
// 301.072 us; speedup vs baseline: 1.2175x; 1.0259x over previous
//
#include <hip/hip_runtime.h>
#include <hip/hip_bf16.h>
#include <stdint.h>

#define B_ 4
#define T_ 2048
#define D_ 1024
#define H_ 16
#define HD_ 64

// softmax computed as 2^(s*log2e): log2(e)/8 folded into Q projection scale
#define QSCALE 0.1803368801111244f

typedef __bf16 bf16_t;
typedef __bf16 bf16x8 __attribute__((ext_vector_type(8)));
typedef __bf16 bf16x4 __attribute__((ext_vector_type(4)));
typedef float f32x4 __attribute__((ext_vector_type(4)));

__device__ __forceinline__ f32x4 mfma16(bf16x8 a, bf16x8 b, f32x4 c) {
  return __builtin_amdgcn_mfma_f32_16x16x32_bf16(a, b, c, 0, 0, 0);
}

__device__ __forceinline__ void gload_lds16(const bf16_t* g, bf16_t* l) {
  __builtin_amdgcn_global_load_lds(
      (const __attribute__((address_space(1))) unsigned int*)g,
      (__attribute__((address_space(3))) unsigned int*)l, 16, 0, 0);
}

__device__ __forceinline__ float exp2g(float x) {
  return __builtin_amdgcn_exp2f(x);
}

// ---------------------------------------------------------------------------
// convert x fp32 -> bf16 (linear)
// ---------------------------------------------------------------------------
__global__ __launch_bounds__(256) void conv_x(const float* __restrict__ x,
                                              bf16_t* __restrict__ xb) {
  size_t i = ((size_t)blockIdx.x * 256 + threadIdx.x) * 8;
  float4 a = *(const float4*)(x + i);
  float4 b = *(const float4*)(x + i + 4);
  bf16x8 v;
  v[0] = (bf16_t)a.x; v[1] = (bf16_t)a.y; v[2] = (bf16_t)a.z; v[3] = (bf16_t)a.w;
  v[4] = (bf16_t)b.x; v[5] = (bf16_t)b.y; v[6] = (bf16_t)b.z; v[7] = (bf16_t)b.w;
  *(bf16x8*)(xb + i) = v;
}

// ---------------------------------------------------------------------------
// convert + transpose W[k][n] fp32 -> Wt[n][k] bf16 (64x64 tiles via LDS)
// ---------------------------------------------------------------------------
__global__ __launch_bounds__(256) void conv_wt3(
    const float* __restrict__ Wq, const float* __restrict__ Wk,
    const float* __restrict__ Wv, bf16_t* __restrict__ WtAll) {
  __shared__ float Ls[64][65];
  const int tid = threadIdx.x;
  const int z = blockIdx.z;
  const float* W = (z == 0) ? Wq : (z == 1) ? Wk : Wv;
  bf16_t* Wt = WtAll + (size_t)z * 1024 * D_;
  const int k0 = blockIdx.y * 64, n0 = blockIdx.x * 64;
  const int rr = tid >> 4, cc = (tid & 15) * 4;
#pragma unroll
  for (int it = 0; it < 4; ++it) {
    int r = rr + it * 16;
    float4 v = *(const float4*)(W + (size_t)(k0 + r) * D_ + n0 + cc);
    Ls[r][cc] = v.x; Ls[r][cc + 1] = v.y; Ls[r][cc + 2] = v.z; Ls[r][cc + 3] = v.w;
  }
  __syncthreads();
#pragma unroll
  for (int it = 0; it < 4; ++it) {
    int nl = rr + it * 16;
    bf16x4 o;
    o[0] = (bf16_t)Ls[cc][nl];     o[1] = (bf16_t)Ls[cc + 1][nl];
    o[2] = (bf16_t)Ls[cc + 2][nl]; o[3] = (bf16_t)Ls[cc + 3][nl];
    *(bf16x4*)(Wt + (size_t)(n0 + nl) * D_ + k0 + cc) = o;
  }
}

// ---------------------------------------------------------------------------
// fused QKV GEMM (round-11 structure + natural V): 128x128 tiles, BK=64,
// global_load_lds staging, mb-fastest XCD map.
// ---------------------------------------------------------------------------
__global__ __launch_bounds__(256) void gemm_qkv(
    const bf16_t* __restrict__ A, const bf16_t* __restrict__ Bt,
    const float* __restrict__ bq, const float* __restrict__ bk,
    const float* __restrict__ bv,
    bf16_t* __restrict__ Qo, bf16_t* __restrict__ Ko, bf16_t* __restrict__ Vo)
{
  __shared__ __align__(16) bf16_t As[128 * 64];
  __shared__ __align__(16) bf16_t Bs[128 * 64];
  const int tid = threadIdx.x, lane = tid & 63, wv = tid >> 6;
  const int wr = wv >> 1, wc = wv & 1;
  const int wg = blockIdx.x;
  const int xcd = wg & 7;
  const int local = wg >> 3;                    // 0..191
  const int mb = xcd * 8 + (local & 7);         // 64 mb, 8 per XCD
  const int nb = local >> 3;                    // 0..23
  const int m0 = mb * 128, n0 = nb * 128;
  const int mode = nb >> 3;                     // 0..2
  const int lr = lane & 15, lg = lane >> 4;
  const int srow = wv * 8 + (lane >> 3);
  const int scol = (lane & 7) * 8;

  f32x4 acc[4][4] = {};

  for (int k0 = 0; k0 < D_; k0 += 64) {
    __syncthreads();
#pragma unroll
    for (int i = 0; i < 4; ++i) {
      gload_lds16(A + (size_t)(m0 + i * 32 + srow) * D_ + k0 + scol,
                  &As[(i * 32 + wv * 8) * 64]);
      gload_lds16(Bt + (size_t)(n0 + i * 32 + srow) * D_ + k0 + scol,
                  &Bs[(i * 32 + wv * 8) * 64]);
    }
    __syncthreads();

#pragma unroll
    for (int ks = 0; ks < 2; ++ks) {
      bf16x8 af[4], bfr[4];
#pragma unroll
      for (int i = 0; i < 4; ++i)
        af[i] = *(const bf16x8*)&As[(wr * 64 + i * 16 + lr) * 64 + ks * 32 + lg * 8];
#pragma unroll
      for (int j = 0; j < 4; ++j)
        bfr[j] = *(const bf16x8*)&Bs[(wc * 64 + j * 16 + lr) * 64 + ks * 32 + lg * 8];
#pragma unroll
      for (int i = 0; i < 4; ++i)
#pragma unroll
        for (int j = 0; j < 4; ++j)
          acc[i][j] = mfma16(af[i], bfr[j], acc[i][j]);
    }
  }

  bf16_t* out = (mode == 0) ? Qo : (mode == 1) ? Ko : Vo;
  const float* bias = (mode == 0) ? bq : (mode == 1) ? bk : bv;
  const float scale = (mode == 0) ? QSCALE : 1.0f;
  const int nl0 = n0 - mode * 1024;
#pragma unroll
  for (int j = 0; j < 4; ++j) {
    int n = nl0 + wc * 64 + j * 16 + lr;
    float bval = bias[n];
    int h = n >> 6, d = n & 63;
#pragma unroll
    for (int i = 0; i < 4; ++i)
#pragma unroll
      for (int r = 0; r < 4; ++r) {
        int m = m0 + wr * 64 + i * 16 + lg * 4 + r;
        int b = m >> 11, t = m & (T_ - 1);
        float val = (acc[i][j][r] + bval) * scale;
        out[(((size_t)(b * H_ + h)) * T_ + t) * HD_ + d] = (bf16_t)val;
      }
  }
}

// ---------------------------------------------------------------------------
// fallback GEMM (fp32 inputs) — natural output only
// ---------------------------------------------------------------------------
__global__ __launch_bounds__(256) void qkv_gemm_f32(
    const float* __restrict__ x, const float* __restrict__ W,
    const float* __restrict__ bias, bf16_t* __restrict__ out, float scale)
{
  __shared__ bf16_t As[128][40];
  __shared__ bf16_t Bs[128][40];
  const int tid = threadIdx.x, lane = tid & 63, wv = tid >> 6;
  const int wr = wv >> 1, wc = wv & 1;
  const int m0 = blockIdx.y * 128, n0 = blockIdx.x * 128;
  const int lr = lane & 15, lg = lane >> 4;
  f32x4 acc[4][4] = {};
  const int xr = tid >> 3, xc = tid & 7;
  const int wk = tid >> 5, wn = tid & 31;

  for (int k0 = 0; k0 < D_; k0 += 32) {
    __syncthreads();
#pragma unroll
    for (int it = 0; it < 4; ++it) {
      int r = xr + it * 32;
      float4 v = *(const float4*)(x + (size_t)(m0 + r) * D_ + k0 + xc * 4);
      bf16_t* dst = &As[r][xc * 4];
      dst[0] = (bf16_t)v.x; dst[1] = (bf16_t)v.y;
      dst[2] = (bf16_t)v.z; dst[3] = (bf16_t)v.w;
    }
#pragma unroll
    for (int it = 0; it < 4; ++it) {
      int k = wk + it * 8;
      float4 v = *(const float4*)(W + (size_t)(k0 + k) * D_ + n0 + wn * 4);
      Bs[wn * 4 + 0][k] = (bf16_t)v.x;
      Bs[wn * 4 + 1][k] = (bf16_t)v.y;
      Bs[wn * 4 + 2][k] = (bf16_t)v.z;
      Bs[wn * 4 + 3][k] = (bf16_t)v.w;
    }
    __syncthreads();
    bf16x8 af[4], bfr[4];
#pragma unroll
    for (int i = 0; i < 4; ++i) af[i]  = *(const bf16x8*)&As[wr * 64 + i * 16 + lr][lg * 8];
#pragma unroll
    for (int j = 0; j < 4; ++j) bfr[j] = *(const bf16x8*)&Bs[wc * 64 + j * 16 + lr][lg * 8];
#pragma unroll
    for (int i = 0; i < 4; ++i)
#pragma unroll
      for (int j = 0; j < 4; ++j)
        acc[i][j] = mfma16(af[i], bfr[j], acc[i][j]);
  }

#pragma unroll
  for (int j = 0; j < 4; ++j) {
    int n = n0 + wc * 64 + j * 16 + lr;
    float bval = bias[n];
    int h = n >> 6, d = n & 63;
#pragma unroll
    for (int i = 0; i < 4; ++i)
#pragma unroll
      for (int r = 0; r < 4; ++r) {
        int m = m0 + wr * 64 + i * 16 + lg * 4 + r;
        int b = m >> 11, t = m & (T_ - 1);
        float val = (acc[i][j][r] + bval) * scale;
        out[(((size_t)(b * H_ + h)) * T_ + t) * HD_ + d] = (bf16_t)val;
      }
  }
}

// ---------------------------------------------------------------------------
// attn_rowsum v3: Lsum[bh,q] += sum_t 2^s. Wave holds 64 q as A-frags;
// streams K TWO 16-row groups per iteration (4 loads in flight, 4 MFMA per
// qq = two independent 2-chains). 1024 blocks = 8 xcd * 8 bh * 8 qc * 2 th.
// ---------------------------------------------------------------------------
__global__ __launch_bounds__(256) void attn_rowsum(
    const bf16_t* __restrict__ Q, const bf16_t* __restrict__ K,
    float* __restrict__ Lsum)
{
  const int tid = threadIdx.x, lane = tid & 63, wv = tid >> 6;
  const int lr = lane & 15, lg = lane >> 4;
  const int wg = blockIdx.x;
  const int p_ = wg >> 3;
  const int bh = (wg & 7) * 8 + (p_ >> 4);
  const int rem = p_ & 15;
  const int qc = rem >> 1;
  const int th = rem & 1;
  const int q0w = qc * 256 + wv * 64;

  const bf16_t* Qb = Q + (size_t)bh * T_ * HD_;
  const bf16_t* Kb = K + (size_t)bh * T_ * HD_;

  bf16x8 qa[4][2];
#pragma unroll
  for (int qq = 0; qq < 4; ++qq)
#pragma unroll
    for (int ks = 0; ks < 2; ++ks)
      qa[qq][ks] = *(const bf16x8*)(Qb + (size_t)(q0w + qq * 16 + lr) * HD_ +
                                    ks * 32 + lg * 8);

  float acc[4][4] = {};   // [qq][r] : q = q0w + qq*16 + 4*lg + r

  const int tlo = th * (T_ / 2), thi = tlo + T_ / 2;
  for (int tb = tlo; tb < thi; tb += 64) {
#pragma unroll
    for (int ts = 0; ts < 2; ++ts) {
      const int tA = tb + ts * 32 + lr;
      const int tB = tA + 16;
      bf16x8 kA0 = *(const bf16x8*)(Kb + (size_t)tA * HD_ + lg * 8);
      bf16x8 kA1 = *(const bf16x8*)(Kb + (size_t)tA * HD_ + 32 + lg * 8);
      bf16x8 kB0 = *(const bf16x8*)(Kb + (size_t)tB * HD_ + lg * 8);
      bf16x8 kB1 = *(const bf16x8*)(Kb + (size_t)tB * HD_ + 32 + lg * 8);
#pragma unroll
      for (int qq = 0; qq < 4; ++qq) {
        f32x4 sA = {}, sB = {};
        __builtin_amdgcn_s_setprio(1);
        sA = mfma16(qa[qq][0], kA0, sA);
        sA = mfma16(qa[qq][1], kA1, sA);
        sB = mfma16(qa[qq][0], kB0, sB);
        sB = mfma16(qa[qq][1], kB1, sB);
        __builtin_amdgcn_s_setprio(0);
#pragma unroll
        for (int r = 0; r < 4; ++r)
          acc[qq][r] += exp2g(sA[r]) + exp2g(sB[r]);
      }
    }
  }

#pragma unroll
  for (int qq = 0; qq < 4; ++qq)
#pragma unroll
    for (int r = 0; r < 4; ++r) {
      float v = acc[qq][r];
      v += __shfl_xor(v, 1); v += __shfl_xor(v, 2);
      v += __shfl_xor(v, 4); v += __shfl_xor(v, 8);
      acc[qq][r] = v;
    }
  if (lr == 0) {
#pragma unroll
    for (int qq = 0; qq < 4; ++qq)
#pragma unroll
      for (int r = 0; r < 4; ++r)
        atomicAdd(&Lsum[(size_t)bh * T_ + q0w + qq * 16 + lg * 4 + r],
                  acc[qq][r]);
  }
}

// ---------------------------------------------------------------------------
// inv_l: Lsum -> 1/Lsum in place. 131072 floats, float4 per thread.
// ---------------------------------------------------------------------------
__global__ __launch_bounds__(256) void inv_l(float* __restrict__ L) {
  size_t i = ((size_t)blockIdx.x * 256 + threadIdx.x) * 4;
  float4 v = *(float4*)(L + i);
  v.x = 1.f / v.x; v.y = 1.f / v.y; v.z = 1.f / v.z; v.w = 1.f / v.w;
  *(float4*)(L + i) = v;
}

// ---------------------------------------------------------------------------
// attn_colsum v3: colsum[b,t] += sum_q 2^s * Linv[q]. Wave holds 128 t as
// A-frags; streams Q TWO 16-row groups per iteration (4 MFMA per tt).
// 1024 blocks = 8 xcd * 8 bh * 4 tc * 4 qs. No LDS, no barriers.
// ---------------------------------------------------------------------------
__global__ __launch_bounds__(256) void attn_colsum(
    const bf16_t* __restrict__ Q, const bf16_t* __restrict__ K,
    const float* __restrict__ Linv, float* __restrict__ colsum)
{
  const int tid = threadIdx.x, lane = tid & 63, wv = tid >> 6;
  const int lr = lane & 15, lg = lane >> 4;
  const int wg = blockIdx.x;
  const int p_ = wg >> 3;
  const int bh = (wg & 7) * 8 + (p_ >> 4);
  const int rem = p_ & 15;
  const int tc = rem >> 2;
  const int qs = rem & 3;
  const int b = bh >> 4;
  const int t0w = tc * 512 + wv * 128;

  const bf16_t* Qb = Q + (size_t)bh * T_ * HD_;
  const bf16_t* Kb = K + (size_t)bh * T_ * HD_;
  const float* Lb = Linv + (size_t)bh * T_;

  bf16x8 kf[8][2];
#pragma unroll
  for (int tt = 0; tt < 8; ++tt)
#pragma unroll
    for (int ks = 0; ks < 2; ++ks)
      kf[tt][ks] = *(const bf16x8*)(Kb + (size_t)(t0w + tt * 16 + lr) * HD_ +
                                    ks * 32 + lg * 8);

  float acc[8][4] = {};   // [tt][r] : t = t0w + tt*16 + 4*lg + r

  const int qlo = qs * (T_ / 4), qhi = qlo + T_ / 4;
  for (int qb = qlo; qb < qhi; qb += 64) {
#pragma unroll
    for (int qp = 0; qp < 2; ++qp) {
      const int qA = qb + qp * 32 + lr;
      const int qB = qA + 16;
      bf16x8 qA0 = *(const bf16x8*)(Qb + (size_t)qA * HD_ + lg * 8);
      bf16x8 qA1 = *(const bf16x8*)(Qb + (size_t)qA * HD_ + 32 + lg * 8);
      bf16x8 qB0 = *(const bf16x8*)(Qb + (size_t)qB * HD_ + lg * 8);
      bf16x8 qB1 = *(const bf16x8*)(Qb + (size_t)qB * HD_ + 32 + lg * 8);
      const float lvA = Lb[qA];
      const float lvB = Lb[qB];
#pragma unroll
      for (int tt = 0; tt < 8; ++tt) {
        f32x4 sA = {}, sB = {};
        __builtin_amdgcn_s_setprio(1);
        sA = mfma16(kf[tt][0], qA0, sA);
        sA = mfma16(kf[tt][1], qA1, sA);
        sB = mfma16(kf[tt][0], qB0, sB);
        sB = mfma16(kf[tt][1], qB1, sB);
        __builtin_amdgcn_s_setprio(0);
#pragma unroll
        for (int r = 0; r < 4; ++r) {
          acc[tt][r] = fmaf(exp2g(sA[r]), lvA, acc[tt][r]);
          acc[tt][r] = fmaf(exp2g(sB[r]), lvB, acc[tt][r]);
        }
      }
    }
  }

#pragma unroll
  for (int tt = 0; tt < 8; ++tt)
#pragma unroll
    for (int r = 0; r < 4; ++r) {
      float v = acc[tt][r];
      v += __shfl_xor(v, 1); v += __shfl_xor(v, 2);
      v += __shfl_xor(v, 4); v += __shfl_xor(v, 8);
      acc[tt][r] = v;
    }
  if (lr == 0) {
#pragma unroll
    for (int tt = 0; tt < 8; ++tt)
#pragma unroll
      for (int r = 0; r < 4; ++r)
        atomicAdd(&colsum[b * T_ + t0w + tt * 16 + lg * 4 + r], acc[tt][r]);
  }
}

// ---------------------------------------------------------------------------
// attn_w2 v3: w2[bh,k] += sum_t (colsum[b,t]/32768) * 2^s * Linv[t].
// Same structure as attn_colsum v3 with per-row weight changed.
// ---------------------------------------------------------------------------
__global__ __launch_bounds__(256) void attn_w2(
    const bf16_t* __restrict__ Q, const bf16_t* __restrict__ K,
    const float* __restrict__ Linv, const float* __restrict__ CS,
    float* __restrict__ w2)
{
  const int tid = threadIdx.x, lane = tid & 63, wv = tid >> 6;
  const int lr = lane & 15, lg = lane >> 4;
  const int wg = blockIdx.x;
  const int p_ = wg >> 3;
  const int bh = (wg & 7) * 8 + (p_ >> 4);
  const int rem = p_ & 15;
  const int tc = rem >> 2;
  const int qs = rem & 3;
  const int b = bh >> 4;
  const int t0w = tc * 512 + wv * 128;

  const bf16_t* Qb = Q + (size_t)bh * T_ * HD_;
  const bf16_t* Kb = K + (size_t)bh * T_ * HD_;
  const float* Lb = Linv + (size_t)bh * T_;
  const float* Cb = CS + (size_t)b * T_;

  bf16x8 kf[8][2];
#pragma unroll
  for (int tt = 0; tt < 8; ++tt)
#pragma unroll
    for (int ks = 0; ks < 2; ++ks)
      kf[tt][ks] = *(const bf16x8*)(Kb + (size_t)(t0w + tt * 16 + lr) * HD_ +
                                    ks * 32 + lg * 8);

  float acc[8][4] = {};

  const int qlo = qs * (T_ / 4), qhi = qlo + T_ / 4;
  for (int qb = qlo; qb < qhi; qb += 64) {
#pragma unroll
    for (int qp = 0; qp < 2; ++qp) {
      const int qA = qb + qp * 32 + lr;
      const int qB = qA + 16;
      bf16x8 qA0 = *(const bf16x8*)(Qb + (size_t)qA * HD_ + lg * 8);
      bf16x8 qA1 = *(const bf16x8*)(Qb + (size_t)qA * HD_ + 32 + lg * 8);
      bf16x8 qB0 = *(const bf16x8*)(Qb + (size_t)qB * HD_ + lg * 8);
      bf16x8 qB1 = *(const bf16x8*)(Qb + (size_t)qB * HD_ + 32 + lg * 8);
      const float lvA = Cb[qA] * Lb[qA] * (1.f / 32768.f);
      const float lvB = Cb[qB] * Lb[qB] * (1.f / 32768.f);
#pragma unroll
      for (int tt = 0; tt < 8; ++tt) {
        f32x4 sA = {}, sB = {};
        __builtin_amdgcn_s_setprio(1);
        sA = mfma16(kf[tt][0], qA0, sA);
        sA = mfma16(kf[tt][1], qA1, sA);
        sB = mfma16(kf[tt][0], qB0, sB);
        sB = mfma16(kf[tt][1], qB1, sB);
        __builtin_amdgcn_s_setprio(0);
#pragma unroll
        for (int r = 0; r < 4; ++r) {
          acc[tt][r] = fmaf(exp2g(sA[r]), lvA, acc[tt][r]);
          acc[tt][r] = fmaf(exp2g(sB[r]), lvB, acc[tt][r]);
        }
      }
    }
  }

#pragma unroll
  for (int tt = 0; tt < 8; ++tt)
#pragma unroll
    for (int r = 0; r < 4; ++r) {
      float v = acc[tt][r];
      v += __shfl_xor(v, 1); v += __shfl_xor(v, 2);
      v += __shfl_xor(v, 4); v += __shfl_xor(v, 8);
      acc[tt][r] = v;
    }
  if (lr == 0) {
#pragma unroll
    for (int tt = 0; tt < 8; ++tt)
#pragma unroll
      for (int r = 0; r < 4; ++r)
        atomicAdd(&w2[(size_t)bh * T_ + t0w + tt * 16 + lg * 4 + r],
                  acc[tt][r]);
  }
}

// ---------------------------------------------------------------------------
// pool_wv: pre[b, h*64+d] += sum_{s in chunk} w2[bh,s] * V[bh,s,d]
// ---------------------------------------------------------------------------
__global__ __launch_bounds__(256) void pool_wv(
    const bf16_t* __restrict__ V, const float* __restrict__ W2,
    float* __restrict__ pre)
{
  __shared__ float sm[256];
  const int wg = blockIdx.x;
  const int bh = wg >> 3, sc = wg & 7;
  const int b = bh >> 4, h = bh & 15;
  const int tid = threadIdx.x, d = tid & 63, tg = tid >> 6;
  const bf16_t* Vb = V + (size_t)bh * T_ * HD_ + (size_t)sc * 256 * HD_;
  const float* wb = W2 + (size_t)bh * T_ + sc * 256;
  float acc = 0.f;
  for (int s = tg; s < 256; s += 4)
    acc += wb[s] * (float)Vb[(size_t)s * HD_ + d];
  sm[tid] = acc;
  __syncthreads();
  if (tid < 64) {
    float s = sm[tid] + sm[tid + 64] + sm[tid + 128] + sm[tid + 192];
    atomicAdd(&pre[b * D_ + h * 64 + tid], s);
  }
}

// ---------------------------------------------------------------------------
// out_acc: out[b,d] += sum_{k in chunk} pre[b,k]*Wo[k,d]  (+bo[d] on chunk 0)
// ---------------------------------------------------------------------------
__global__ __launch_bounds__(256) void out_acc(
    const float* __restrict__ pre, const float* __restrict__ Wo,
    const float* __restrict__ bo, float* __restrict__ out)
{
  const int dc = blockIdx.x & 3, kb = blockIdx.x >> 2;
  const int d = dc * 256 + threadIdx.x;
  const int k0 = kb * 32;
  float acc0 = 0.f, acc1 = 0.f, acc2 = 0.f, acc3 = 0.f;
#pragma unroll
  for (int kk = 0; kk < 32; ++kk) {
    const int k = k0 + kk;
    const float w = Wo[(size_t)k * D_ + d];
    acc0 = fmaf(pre[k],            w, acc0);
    acc1 = fmaf(pre[D_ + k],       w, acc1);
    acc2 = fmaf(pre[2 * D_ + k],   w, acc2);
    acc3 = fmaf(pre[3 * D_ + k],   w, acc3);
  }
  if (kb == 0) {
    const float bd = bo[d];
    acc0 += bd; acc1 += bd; acc2 += bd; acc3 += bd;
  }
  atomicAdd(&out[d],           acc0);
  atomicAdd(&out[D_ + d],      acc1);
  atomicAdd(&out[2 * D_ + d],  acc2);
  atomicAdd(&out[3 * D_ + d],  acc3);
}

// ---------------------------------------------------------------------------
extern "C" void kernel_launch(void* const* d_in, const int* in_sizes, int n_in,
                              void* d_out, int out_size, void* d_ws, size_t ws_size,
                              hipStream_t stream)
{
  (void)in_sizes; (void)n_in; (void)out_size;
  const float* x  = (const float*)d_in[0];
  const float* Wq = (const float*)d_in[1];
  const float* bq = (const float*)d_in[2];
  const float* Wk = (const float*)d_in[3];
  const float* bk = (const float*)d_in[4];
  const float* Wv = (const float*)d_in[5];
  const float* bv = (const float*)d_in[6];
  const float* Wo = (const float*)d_in[7];
  const float* bo = (const float*)d_in[8];
  float* out = (float*)d_out;

  char* ws = (char*)d_ws;
  const size_t MB = 1ull << 20;
  const size_t KB = 1024;
  bf16_t* Qw = (bf16_t*)(ws);
  bf16_t* Kw = (bf16_t*)(ws + 16 * MB);
  bf16_t* Vw = (bf16_t*)(ws + 32 * MB);
  bf16_t* XB = (bf16_t*)(ws + 48 * MB);
  const size_t need_fast = 72 * MB;
  const bool fast = ws_size >= need_fast;

  // scalars region (all zeroed in one memset): LV | CS | PRE | W2
  size_t soff = fast ? 70 * MB : 64 * MB;
  float* LV  = (float*)(ws + soff);                    // 512 KB (Lsum->Linv)
  float* CS  = (float*)(ws + soff + 512 * KB);         // 32 KB
  float* PRE = (float*)(ws + soff + 544 * KB);         // 16 KB
  float* W2  = (float*)(ws + soff + 560 * KB);         // 512 KB
  dim3 blk(256, 1, 1);

  if (fast) {
    bf16_t* WtAll = (bf16_t*)(ws + 64 * MB);  // [3072][1024] bf16 = 6 MB
    conv_x<<<dim3((B_ * T_ * D_) / (256 * 8), 1, 1), blk, 0, stream>>>(x, XB);
    conv_wt3<<<dim3(16, 16, 3), blk, 0, stream>>>(Wq, Wk, Wv, WtAll);
    gemm_qkv<<<dim3(1536, 1, 1), blk, 0, stream>>>(XB, WtAll, bq, bk, bv,
                                                   Qw, Kw, Vw);
  } else {
    qkv_gemm_f32<<<dim3(8, 64, 1), blk, 0, stream>>>(x, Wq, bq, Qw, QSCALE);
    qkv_gemm_f32<<<dim3(8, 64, 1), blk, 0, stream>>>(x, Wk, bk, Kw, 1.0f);
    qkv_gemm_f32<<<dim3(8, 64, 1), blk, 0, stream>>>(x, Wv, bv, Vw, 1.0f);
  }

  hipMemsetAsync(LV, 0, 1072 * KB, stream);
  hipMemsetAsync(out, 0, (size_t)B_ * D_ * sizeof(float), stream);

  attn_rowsum<<<dim3(1024, 1, 1), blk, 0, stream>>>(Qw, Kw, LV);
  inv_l<<<dim3((B_ * H_ * T_) / (256 * 4), 1, 1), blk, 0, stream>>>(LV);
  attn_colsum<<<dim3(1024, 1, 1), blk, 0, stream>>>(Qw, Kw, LV, CS);
  attn_w2<<<dim3(1024, 1, 1), blk, 0, stream>>>(Qw, Kw, LV, CS, W2);
  pool_wv<<<dim3(512, 1, 1), blk, 0, stream>>>(Vw, W2, PRE);
  out_acc<<<dim3(128, 1, 1), blk, 0, stream>>>(PRE, Wo, bo, out);
}

// Round 15
// 296.940 us; speedup vs baseline: 1.2345x; 1.0139x over previous
//
#include <hip/hip_runtime.h>
#include <hip/hip_bf16.h>
#include <stdint.h>

#define B_ 4
#define T_ 2048
#define D_ 1024
#define H_ 16
#define HD_ 64

// softmax computed as 2^(s*log2e): log2(e)/8 folded into Q projection scale
#define QSCALE 0.1803368801111244f

typedef __bf16 bf16_t;
typedef __bf16 bf16x8 __attribute__((ext_vector_type(8)));
typedef __bf16 bf16x4 __attribute__((ext_vector_type(4)));
typedef float f32x4 __attribute__((ext_vector_type(4)));

__device__ __forceinline__ f32x4 mfma16(bf16x8 a, bf16x8 b, f32x4 c) {
  return __builtin_amdgcn_mfma_f32_16x16x32_bf16(a, b, c, 0, 0, 0);
}

__device__ __forceinline__ void gload_lds16(const bf16_t* g, bf16_t* l) {
  __builtin_amdgcn_global_load_lds(
      (const __attribute__((address_space(1))) unsigned int*)g,
      (__attribute__((address_space(3))) unsigned int*)l, 16, 0, 0);
}

__device__ __forceinline__ float exp2g(float x) {
  return __builtin_amdgcn_exp2f(x);
}

__device__ __forceinline__ float rcpg(float x) {
  return __builtin_amdgcn_rcpf(x);
}

// ---------------------------------------------------------------------------
// convert x fp32 -> bf16 (linear)
// ---------------------------------------------------------------------------
__global__ __launch_bounds__(256) void conv_x(const float* __restrict__ x,
                                              bf16_t* __restrict__ xb) {
  size_t i = ((size_t)blockIdx.x * 256 + threadIdx.x) * 8;
  float4 a = *(const float4*)(x + i);
  float4 b = *(const float4*)(x + i + 4);
  bf16x8 v;
  v[0] = (bf16_t)a.x; v[1] = (bf16_t)a.y; v[2] = (bf16_t)a.z; v[3] = (bf16_t)a.w;
  v[4] = (bf16_t)b.x; v[5] = (bf16_t)b.y; v[6] = (bf16_t)b.z; v[7] = (bf16_t)b.w;
  *(bf16x8*)(xb + i) = v;
}

// ---------------------------------------------------------------------------
// convert + transpose W[k][n] fp32 -> Wt[n][k] bf16 (64x64 tiles via LDS)
// ---------------------------------------------------------------------------
__global__ __launch_bounds__(256) void conv_wt3(
    const float* __restrict__ Wq, const float* __restrict__ Wk,
    const float* __restrict__ Wv, bf16_t* __restrict__ WtAll) {
  __shared__ float Ls[64][65];
  const int tid = threadIdx.x;
  const int z = blockIdx.z;
  const float* W = (z == 0) ? Wq : (z == 1) ? Wk : Wv;
  bf16_t* Wt = WtAll + (size_t)z * 1024 * D_;
  const int k0 = blockIdx.y * 64, n0 = blockIdx.x * 64;
  const int rr = tid >> 4, cc = (tid & 15) * 4;
#pragma unroll
  for (int it = 0; it < 4; ++it) {
    int r = rr + it * 16;
    float4 v = *(const float4*)(W + (size_t)(k0 + r) * D_ + n0 + cc);
    Ls[r][cc] = v.x; Ls[r][cc + 1] = v.y; Ls[r][cc + 2] = v.z; Ls[r][cc + 3] = v.w;
  }
  __syncthreads();
#pragma unroll
  for (int it = 0; it < 4; ++it) {
    int nl = rr + it * 16;
    bf16x4 o;
    o[0] = (bf16_t)Ls[cc][nl];     o[1] = (bf16_t)Ls[cc + 1][nl];
    o[2] = (bf16_t)Ls[cc + 2][nl]; o[3] = (bf16_t)Ls[cc + 3][nl];
    *(bf16x4*)(Wt + (size_t)(n0 + nl) * D_ + k0 + cc) = o;
  }
}

// ---------------------------------------------------------------------------
// fused QKV GEMM v2: 256x128 tiles, 512 threads / 8 waves (4 wr x 2 wc of
// 64x64 sub-tiles), BK=64, global_load_lds staging (48 KB/step feeds 256
// wave-MFMAs vs 128^2's 32KB/128 = 27% less staging per MFMA). Grid 768;
// each XCD owns 4 contiguous mb x all 24 nb, mb-fastest.
// mode = nb>>3: 0->Q (scaled QSCALE), 1->K, 2->V. Natural [bh][t][d] output.
// ---------------------------------------------------------------------------
__global__ __launch_bounds__(512) void gemm_qkv(
    const bf16_t* __restrict__ A, const bf16_t* __restrict__ Bt,
    const float* __restrict__ bq, const float* __restrict__ bk,
    const float* __restrict__ bv,
    bf16_t* __restrict__ Qo, bf16_t* __restrict__ Ko, bf16_t* __restrict__ Vo)
{
  __shared__ __align__(16) bf16_t As[256 * 64];   // 32 KB
  __shared__ __align__(16) bf16_t Bs[128 * 64];   // 16 KB
  const int tid = threadIdx.x, lane = tid & 63, wv = tid >> 6;
  const int wr = wv >> 1, wc = wv & 1;
  const int wg = blockIdx.x;
  const int xcd = wg & 7;
  const int local = wg >> 3;                    // 0..95
  const int mb = xcd * 4 + (local & 3);         // 32 mb, 4 per XCD
  const int nb = local >> 2;                    // 0..23
  const int m0 = mb * 256, n0 = nb * 128;
  const int mode = nb >> 3;                     // 0..2
  const int lr = lane & 15, lg = lane >> 4;
  const int srow = tid >> 3;                    // 0..63
  const int scol = (tid & 7) * 8;               // k elems

  f32x4 acc[4][4] = {};

  for (int k0 = 0; k0 < D_; k0 += 64) {
    __syncthreads();
#pragma unroll
    for (int i = 0; i < 4; ++i)
      gload_lds16(A + (size_t)(m0 + i * 64 + srow) * D_ + k0 + scol,
                  &As[(i * 64 + (wv << 3)) * 64]);
#pragma unroll
    for (int i = 0; i < 2; ++i)
      gload_lds16(Bt + (size_t)(n0 + i * 64 + srow) * D_ + k0 + scol,
                  &Bs[(i * 64 + (wv << 3)) * 64]);
    __syncthreads();

#pragma unroll
    for (int ks = 0; ks < 2; ++ks) {
      bf16x8 af[4], bfr[4];
#pragma unroll
      for (int i = 0; i < 4; ++i)
        af[i] = *(const bf16x8*)&As[(wr * 64 + i * 16 + lr) * 64 + ks * 32 + lg * 8];
#pragma unroll
      for (int j = 0; j < 4; ++j)
        bfr[j] = *(const bf16x8*)&Bs[(wc * 64 + j * 16 + lr) * 64 + ks * 32 + lg * 8];
#pragma unroll
      for (int i = 0; i < 4; ++i)
#pragma unroll
        for (int j = 0; j < 4; ++j)
          acc[i][j] = mfma16(af[i], bfr[j], acc[i][j]);
    }
  }

  bf16_t* out = (mode == 0) ? Qo : (mode == 1) ? Ko : Vo;
  const float* bias = (mode == 0) ? bq : (mode == 1) ? bk : bv;
  const float scale = (mode == 0) ? QSCALE : 1.0f;
  const int nl0 = n0 - mode * 1024;
#pragma unroll
  for (int j = 0; j < 4; ++j) {
    int n = nl0 + wc * 64 + j * 16 + lr;
    float bval = bias[n];
    int h = n >> 6, d = n & 63;
#pragma unroll
    for (int i = 0; i < 4; ++i)
#pragma unroll
      for (int r = 0; r < 4; ++r) {
        int m = m0 + wr * 64 + i * 16 + lg * 4 + r;
        int b = m >> 11, t = m & (T_ - 1);
        float val = (acc[i][j][r] + bval) * scale;
        out[(((size_t)(b * H_ + h)) * T_ + t) * HD_ + d] = (bf16_t)val;
      }
  }
}

// ---------------------------------------------------------------------------
// fallback GEMM (fp32 inputs) — natural output only
// ---------------------------------------------------------------------------
__global__ __launch_bounds__(256) void qkv_gemm_f32(
    const float* __restrict__ x, const float* __restrict__ W,
    const float* __restrict__ bias, bf16_t* __restrict__ out, float scale)
{
  __shared__ bf16_t As[128][40];
  __shared__ bf16_t Bs[128][40];
  const int tid = threadIdx.x, lane = tid & 63, wv = tid >> 6;
  const int wr = wv >> 1, wc = wv & 1;
  const int m0 = blockIdx.y * 128, n0 = blockIdx.x * 128;
  const int lr = lane & 15, lg = lane >> 4;
  f32x4 acc[4][4] = {};
  const int xr = tid >> 3, xc = tid & 7;
  const int wk = tid >> 5, wn = tid & 31;

  for (int k0 = 0; k0 < D_; k0 += 32) {
    __syncthreads();
#pragma unroll
    for (int it = 0; it < 4; ++it) {
      int r = xr + it * 32;
      float4 v = *(const float4*)(x + (size_t)(m0 + r) * D_ + k0 + xc * 4);
      bf16_t* dst = &As[r][xc * 4];
      dst[0] = (bf16_t)v.x; dst[1] = (bf16_t)v.y;
      dst[2] = (bf16_t)v.z; dst[3] = (bf16_t)v.w;
    }
#pragma unroll
    for (int it = 0; it < 4; ++it) {
      int k = wk + it * 8;
      float4 v = *(const float4*)(W + (size_t)(k0 + k) * D_ + n0 + wn * 4);
      Bs[wn * 4 + 0][k] = (bf16_t)v.x;
      Bs[wn * 4 + 1][k] = (bf16_t)v.y;
      Bs[wn * 4 + 2][k] = (bf16_t)v.z;
      Bs[wn * 4 + 3][k] = (bf16_t)v.w;
    }
    __syncthreads();
    bf16x8 af[4], bfr[4];
#pragma unroll
    for (int i = 0; i < 4; ++i) af[i]  = *(const bf16x8*)&As[wr * 64 + i * 16 + lr][lg * 8];
#pragma unroll
    for (int j = 0; j < 4; ++j) bfr[j] = *(const bf16x8*)&Bs[wc * 64 + j * 16 + lr][lg * 8];
#pragma unroll
    for (int i = 0; i < 4; ++i)
#pragma unroll
      for (int j = 0; j < 4; ++j)
        acc[i][j] = mfma16(af[i], bfr[j], acc[i][j]);
  }

#pragma unroll
  for (int j = 0; j < 4; ++j) {
    int n = n0 + wc * 64 + j * 16 + lr;
    float bval = bias[n];
    int h = n >> 6, d = n & 63;
#pragma unroll
    for (int i = 0; i < 4; ++i)
#pragma unroll
      for (int r = 0; r < 4; ++r) {
        int m = m0 + wr * 64 + i * 16 + lg * 4 + r;
        int b = m >> 11, t = m & (T_ - 1);
        float val = (acc[i][j][r] + bval) * scale;
        out[(((size_t)(b * H_ + h)) * T_ + t) * HD_ + d] = (bf16_t)val;
      }
  }
}

// ---------------------------------------------------------------------------
// attn_rowsum: Lsum[bh,q] += sum_t 2^s. Wave holds 64 q as A-frags;
// streams K two 16-row groups per iteration. 1024 blocks.
// ---------------------------------------------------------------------------
__global__ __launch_bounds__(256) void attn_rowsum(
    const bf16_t* __restrict__ Q, const bf16_t* __restrict__ K,
    float* __restrict__ Lsum)
{
  const int tid = threadIdx.x, lane = tid & 63, wv = tid >> 6;
  const int lr = lane & 15, lg = lane >> 4;
  const int wg = blockIdx.x;
  const int p_ = wg >> 3;
  const int bh = (wg & 7) * 8 + (p_ >> 4);
  const int rem = p_ & 15;
  const int qc = rem >> 1;
  const int th = rem & 1;
  const int q0w = qc * 256 + wv * 64;

  const bf16_t* Qb = Q + (size_t)bh * T_ * HD_;
  const bf16_t* Kb = K + (size_t)bh * T_ * HD_;

  bf16x8 qa[4][2];
#pragma unroll
  for (int qq = 0; qq < 4; ++qq)
#pragma unroll
    for (int ks = 0; ks < 2; ++ks)
      qa[qq][ks] = *(const bf16x8*)(Qb + (size_t)(q0w + qq * 16 + lr) * HD_ +
                                    ks * 32 + lg * 8);

  float acc[4][4] = {};   // [qq][r] : q = q0w + qq*16 + 4*lg + r

  const int tlo = th * (T_ / 2), thi = tlo + T_ / 2;
  for (int tb = tlo; tb < thi; tb += 64) {
#pragma unroll
    for (int ts = 0; ts < 2; ++ts) {
      const int tA = tb + ts * 32 + lr;
      const int tB = tA + 16;
      bf16x8 kA0 = *(const bf16x8*)(Kb + (size_t)tA * HD_ + lg * 8);
      bf16x8 kA1 = *(const bf16x8*)(Kb + (size_t)tA * HD_ + 32 + lg * 8);
      bf16x8 kB0 = *(const bf16x8*)(Kb + (size_t)tB * HD_ + lg * 8);
      bf16x8 kB1 = *(const bf16x8*)(Kb + (size_t)tB * HD_ + 32 + lg * 8);
#pragma unroll
      for (int qq = 0; qq < 4; ++qq) {
        f32x4 sA = {}, sB = {};
        __builtin_amdgcn_s_setprio(1);
        sA = mfma16(qa[qq][0], kA0, sA);
        sA = mfma16(qa[qq][1], kA1, sA);
        sB = mfma16(qa[qq][0], kB0, sB);
        sB = mfma16(qa[qq][1], kB1, sB);
        __builtin_amdgcn_s_setprio(0);
#pragma unroll
        for (int r = 0; r < 4; ++r)
          acc[qq][r] += exp2g(sA[r]) + exp2g(sB[r]);
      }
    }
  }

#pragma unroll
  for (int qq = 0; qq < 4; ++qq)
#pragma unroll
    for (int r = 0; r < 4; ++r) {
      float v = acc[qq][r];
      v += __shfl_xor(v, 1); v += __shfl_xor(v, 2);
      v += __shfl_xor(v, 4); v += __shfl_xor(v, 8);
      acc[qq][r] = v;
    }
  if (lr == 0) {
#pragma unroll
    for (int qq = 0; qq < 4; ++qq)
#pragma unroll
      for (int r = 0; r < 4; ++r)
        atomicAdd(&Lsum[(size_t)bh * T_ + q0w + qq * 16 + lg * 4 + r],
                  acc[qq][r]);
  }
}

// ---------------------------------------------------------------------------
// attn_colsum: colsum[b,t] += sum_q 2^s / Lsum[q]  (rcp folded in).
// Wave holds 128 t; streams Q two 16-row groups per iteration. 1024 blocks.
// ---------------------------------------------------------------------------
__global__ __launch_bounds__(256) void attn_colsum(
    const bf16_t* __restrict__ Q, const bf16_t* __restrict__ K,
    const float* __restrict__ Lsum, float* __restrict__ colsum)
{
  const int tid = threadIdx.x, lane = tid & 63, wv = tid >> 6;
  const int lr = lane & 15, lg = lane >> 4;
  const int wg = blockIdx.x;
  const int p_ = wg >> 3;
  const int bh = (wg & 7) * 8 + (p_ >> 4);
  const int rem = p_ & 15;
  const int tc = rem >> 2;
  const int qs = rem & 3;
  const int b = bh >> 4;
  const int t0w = tc * 512 + wv * 128;

  const bf16_t* Qb = Q + (size_t)bh * T_ * HD_;
  const bf16_t* Kb = K + (size_t)bh * T_ * HD_;
  const float* Lb = Lsum + (size_t)bh * T_;

  bf16x8 kf[8][2];
#pragma unroll
  for (int tt = 0; tt < 8; ++tt)
#pragma unroll
    for (int ks = 0; ks < 2; ++ks)
      kf[tt][ks] = *(const bf16x8*)(Kb + (size_t)(t0w + tt * 16 + lr) * HD_ +
                                    ks * 32 + lg * 8);

  float acc[8][4] = {};   // [tt][r] : t = t0w + tt*16 + 4*lg + r

  const int qlo = qs * (T_ / 4), qhi = qlo + T_ / 4;
  for (int qb = qlo; qb < qhi; qb += 64) {
#pragma unroll
    for (int qp = 0; qp < 2; ++qp) {
      const int qA = qb + qp * 32 + lr;
      const int qB = qA + 16;
      bf16x8 qA0 = *(const bf16x8*)(Qb + (size_t)qA * HD_ + lg * 8);
      bf16x8 qA1 = *(const bf16x8*)(Qb + (size_t)qA * HD_ + 32 + lg * 8);
      bf16x8 qB0 = *(const bf16x8*)(Qb + (size_t)qB * HD_ + lg * 8);
      bf16x8 qB1 = *(const bf16x8*)(Qb + (size_t)qB * HD_ + 32 + lg * 8);
      const float lvA = rcpg(Lb[qA]);
      const float lvB = rcpg(Lb[qB]);
#pragma unroll
      for (int tt = 0; tt < 8; ++tt) {
        f32x4 sA = {}, sB = {};
        __builtin_amdgcn_s_setprio(1);
        sA = mfma16(kf[tt][0], qA0, sA);
        sA = mfma16(kf[tt][1], qA1, sA);
        sB = mfma16(kf[tt][0], qB0, sB);
        sB = mfma16(kf[tt][1], qB1, sB);
        __builtin_amdgcn_s_setprio(0);
#pragma unroll
        for (int r = 0; r < 4; ++r) {
          acc[tt][r] = fmaf(exp2g(sA[r]), lvA, acc[tt][r]);
          acc[tt][r] = fmaf(exp2g(sB[r]), lvB, acc[tt][r]);
        }
      }
    }
  }

#pragma unroll
  for (int tt = 0; tt < 8; ++tt)
#pragma unroll
    for (int r = 0; r < 4; ++r) {
      float v = acc[tt][r];
      v += __shfl_xor(v, 1); v += __shfl_xor(v, 2);
      v += __shfl_xor(v, 4); v += __shfl_xor(v, 8);
      acc[tt][r] = v;
    }
  if (lr == 0) {
#pragma unroll
    for (int tt = 0; tt < 8; ++tt)
#pragma unroll
      for (int r = 0; r < 4; ++r)
        atomicAdd(&colsum[b * T_ + t0w + tt * 16 + lg * 4 + r], acc[tt][r]);
  }
}

// ---------------------------------------------------------------------------
// attn_w2: w2[bh,k] += sum_t (colsum[b,t]/32768) * 2^s / Lsum[t].
// ---------------------------------------------------------------------------
__global__ __launch_bounds__(256) void attn_w2(
    const bf16_t* __restrict__ Q, const bf16_t* __restrict__ K,
    const float* __restrict__ Lsum, const float* __restrict__ CS,
    float* __restrict__ w2)
{
  const int tid = threadIdx.x, lane = tid & 63, wv = tid >> 6;
  const int lr = lane & 15, lg = lane >> 4;
  const int wg = blockIdx.x;
  const int p_ = wg >> 3;
  const int bh = (wg & 7) * 8 + (p_ >> 4);
  const int rem = p_ & 15;
  const int tc = rem >> 2;
  const int qs = rem & 3;
  const int b = bh >> 4;
  const int t0w = tc * 512 + wv * 128;

  const bf16_t* Qb = Q + (size_t)bh * T_ * HD_;
  const bf16_t* Kb = K + (size_t)bh * T_ * HD_;
  const float* Lb = Lsum + (size_t)bh * T_;
  const float* Cb = CS + (size_t)b * T_;

  bf16x8 kf[8][2];
#pragma unroll
  for (int tt = 0; tt < 8; ++tt)
#pragma unroll
    for (int ks = 0; ks < 2; ++ks)
      kf[tt][ks] = *(const bf16x8*)(Kb + (size_t)(t0w + tt * 16 + lr) * HD_ +
                                    ks * 32 + lg * 8);

  float acc[8][4] = {};

  const int qlo = qs * (T_ / 4), qhi = qlo + T_ / 4;
  for (int qb = qlo; qb < qhi; qb += 64) {
#pragma unroll
    for (int qp = 0; qp < 2; ++qp) {
      const int qA = qb + qp * 32 + lr;
      const int qB = qA + 16;
      bf16x8 qA0 = *(const bf16x8*)(Qb + (size_t)qA * HD_ + lg * 8);
      bf16x8 qA1 = *(const bf16x8*)(Qb + (size_t)qA * HD_ + 32 + lg * 8);
      bf16x8 qB0 = *(const bf16x8*)(Qb + (size_t)qB * HD_ + lg * 8);
      bf16x8 qB1 = *(const bf16x8*)(Qb + (size_t)qB * HD_ + 32 + lg * 8);
      const float lvA = Cb[qA] * rcpg(Lb[qA]) * (1.f / 32768.f);
      const float lvB = Cb[qB] * rcpg(Lb[qB]) * (1.f / 32768.f);
#pragma unroll
      for (int tt = 0; tt < 8; ++tt) {
        f32x4 sA = {}, sB = {};
        __builtin_amdgcn_s_setprio(1);
        sA = mfma16(kf[tt][0], qA0, sA);
        sA = mfma16(kf[tt][1], qA1, sA);
        sB = mfma16(kf[tt][0], qB0, sB);
        sB = mfma16(kf[tt][1], qB1, sB);
        __builtin_amdgcn_s_setprio(0);
#pragma unroll
        for (int r = 0; r < 4; ++r) {
          acc[tt][r] = fmaf(exp2g(sA[r]), lvA, acc[tt][r]);
          acc[tt][r] = fmaf(exp2g(sB[r]), lvB, acc[tt][r]);
        }
      }
    }
  }

#pragma unroll
  for (int tt = 0; tt < 8; ++tt)
#pragma unroll
    for (int r = 0; r < 4; ++r) {
      float v = acc[tt][r];
      v += __shfl_xor(v, 1); v += __shfl_xor(v, 2);
      v += __shfl_xor(v, 4); v += __shfl_xor(v, 8);
      acc[tt][r] = v;
    }
  if (lr == 0) {
#pragma unroll
    for (int tt = 0; tt < 8; ++tt)
#pragma unroll
      for (int r = 0; r < 4; ++r)
        atomicAdd(&w2[(size_t)bh * T_ + t0w + tt * 16 + lg * 4 + r],
                  acc[tt][r]);
  }
}

// ---------------------------------------------------------------------------
// pool_wv: pre[b, h*64+d] += sum_{s in chunk} w2[bh,s] * V[bh,s,d]
// ---------------------------------------------------------------------------
__global__ __launch_bounds__(256) void pool_wv(
    const bf16_t* __restrict__ V, const float* __restrict__ W2,
    float* __restrict__ pre)
{
  __shared__ float sm[256];
  const int wg = blockIdx.x;
  const int bh = wg >> 3, sc = wg & 7;
  const int b = bh >> 4, h = bh & 15;
  const int tid = threadIdx.x, d = tid & 63, tg = tid >> 6;
  const bf16_t* Vb = V + (size_t)bh * T_ * HD_ + (size_t)sc * 256 * HD_;
  const float* wb = W2 + (size_t)bh * T_ + sc * 256;
  float acc = 0.f;
  for (int s = tg; s < 256; s += 4)
    acc += wb[s] * (float)Vb[(size_t)s * HD_ + d];
  sm[tid] = acc;
  __syncthreads();
  if (tid < 64) {
    float s = sm[tid] + sm[tid + 64] + sm[tid + 128] + sm[tid + 192];
    atomicAdd(&pre[b * D_ + h * 64 + tid], s);
  }
}

// ---------------------------------------------------------------------------
// out_acc: out[b,d] += sum_{k in chunk} pre[b,k]*Wo[k,d]  (+bo[d] on chunk 0)
// ---------------------------------------------------------------------------
__global__ __launch_bounds__(256) void out_acc(
    const float* __restrict__ pre, const float* __restrict__ Wo,
    const float* __restrict__ bo, float* __restrict__ out)
{
  const int dc = blockIdx.x & 3, kb = blockIdx.x >> 2;
  const int d = dc * 256 + threadIdx.x;
  const int k0 = kb * 32;
  float acc0 = 0.f, acc1 = 0.f, acc2 = 0.f, acc3 = 0.f;
#pragma unroll
  for (int kk = 0; kk < 32; ++kk) {
    const int k = k0 + kk;
    const float w = Wo[(size_t)k * D_ + d];
    acc0 = fmaf(pre[k],            w, acc0);
    acc1 = fmaf(pre[D_ + k],       w, acc1);
    acc2 = fmaf(pre[2 * D_ + k],   w, acc2);
    acc3 = fmaf(pre[3 * D_ + k],   w, acc3);
  }
  if (kb == 0) {
    const float bd = bo[d];
    acc0 += bd; acc1 += bd; acc2 += bd; acc3 += bd;
  }
  atomicAdd(&out[d],           acc0);
  atomicAdd(&out[D_ + d],      acc1);
  atomicAdd(&out[2 * D_ + d],  acc2);
  atomicAdd(&out[3 * D_ + d],  acc3);
}

// ---------------------------------------------------------------------------
extern "C" void kernel_launch(void* const* d_in, const int* in_sizes, int n_in,
                              void* d_out, int out_size, void* d_ws, size_t ws_size,
                              hipStream_t stream)
{
  (void)in_sizes; (void)n_in; (void)out_size;
  const float* x  = (const float*)d_in[0];
  const float* Wq = (const float*)d_in[1];
  const float* bq = (const float*)d_in[2];
  const float* Wk = (const float*)d_in[3];
  const float* bk = (const float*)d_in[4];
  const float* Wv = (const float*)d_in[5];
  const float* bv = (const float*)d_in[6];
  const float* Wo = (const float*)d_in[7];
  const float* bo = (const float*)d_in[8];
  float* out = (float*)d_out;

  char* ws = (char*)d_ws;
  const size_t MB = 1ull << 20;
  const size_t KB = 1024;
  bf16_t* Qw = (bf16_t*)(ws);
  bf16_t* Kw = (bf16_t*)(ws + 16 * MB);
  bf16_t* Vw = (bf16_t*)(ws + 32 * MB);
  bf16_t* XB = (bf16_t*)(ws + 48 * MB);
  const size_t need_fast = 72 * MB;
  const bool fast = ws_size >= need_fast;

  // scalars region (all zeroed in one memset): LV | CS | PRE | W2
  size_t soff = fast ? 70 * MB : 64 * MB;
  float* LV  = (float*)(ws + soff);                    // 512 KB (Lsum)
  float* CS  = (float*)(ws + soff + 512 * KB);         // 32 KB
  float* PRE = (float*)(ws + soff + 544 * KB);         // 16 KB
  float* W2  = (float*)(ws + soff + 560 * KB);         // 512 KB
  dim3 blk(256, 1, 1);

  if (fast) {
    bf16_t* WtAll = (bf16_t*)(ws + 64 * MB);  // [3072][1024] bf16 = 6 MB
    conv_x<<<dim3((B_ * T_ * D_) / (256 * 8), 1, 1), blk, 0, stream>>>(x, XB);
    conv_wt3<<<dim3(16, 16, 3), blk, 0, stream>>>(Wq, Wk, Wv, WtAll);
    gemm_qkv<<<dim3(768, 1, 1), dim3(512, 1, 1), 0, stream>>>(
        XB, WtAll, bq, bk, bv, Qw, Kw, Vw);
  } else {
    qkv_gemm_f32<<<dim3(8, 64, 1), blk, 0, stream>>>(x, Wq, bq, Qw, QSCALE);
    qkv_gemm_f32<<<dim3(8, 64, 1), blk, 0, stream>>>(x, Wk, bk, Kw, 1.0f);
    qkv_gemm_f32<<<dim3(8, 64, 1), blk, 0, stream>>>(x, Wv, bv, Vw, 1.0f);
  }

  hipMemsetAsync(LV, 0, 1072 * KB, stream);
  hipMemsetAsync(out, 0, (size_t)B_ * D_ * sizeof(float), stream);

  attn_rowsum<<<dim3(1024, 1, 1), blk, 0, stream>>>(Qw, Kw, LV);
  attn_colsum<<<dim3(1024, 1, 1), blk, 0, stream>>>(Qw, Kw, LV, CS);
  attn_w2<<<dim3(1024, 1, 1), blk, 0, stream>>>(Qw, Kw, LV, CS, W2);
  pool_wv<<<dim3(512, 1, 1), blk, 0, stream>>>(Vw, W2, PRE);
  out_acc<<<dim3(128, 1, 1), blk, 0, stream>>>(PRE, Wo, bo, out);
}

// Round 17
// 295.557 us; speedup vs baseline: 1.2402x; 1.0047x over previous
//
#include <hip/hip_runtime.h>
#include <hip/hip_bf16.h>
#include <stdint.h>

#define B_ 4
#define T_ 2048
#define D_ 1024
#define H_ 16
#define HD_ 64

// softmax computed as 2^(s*log2e): log2(e)/8 folded into Q projection scale
#define QSCALE 0.1803368801111244f

typedef __bf16 bf16_t;
typedef __bf16 bf16x8 __attribute__((ext_vector_type(8)));
typedef __bf16 bf16x4 __attribute__((ext_vector_type(4)));
typedef float f32x4 __attribute__((ext_vector_type(4)));

__device__ __forceinline__ f32x4 mfma16(bf16x8 a, bf16x8 b, f32x4 c) {
  return __builtin_amdgcn_mfma_f32_16x16x32_bf16(a, b, c, 0, 0, 0);
}

__device__ __forceinline__ void gload_lds16(const bf16_t* g, bf16_t* l) {
  __builtin_amdgcn_global_load_lds(
      (const __attribute__((address_space(1))) unsigned int*)g,
      (__attribute__((address_space(3))) unsigned int*)l, 16, 0, 0);
}

__device__ __forceinline__ float exp2g(float x) {
  return __builtin_amdgcn_exp2f(x);
}

__device__ __forceinline__ float rcpg(float x) {
  return __builtin_amdgcn_rcpf(x);
}

// ---------------------------------------------------------------------------
// conv_all: one launch. Blocks [0,4096): x fp32->bf16 linear (r15 conv_x
// body). Blocks [4096,4864): W[k][n] fp32 -> Wt[n][k] bf16 via 64x64 LDS
// transpose tiles (r15 conv_wt3 body), z = which weight matrix.
// ---------------------------------------------------------------------------
__global__ __launch_bounds__(256) void conv_all(
    const float* __restrict__ x,
    const float* __restrict__ Wq, const float* __restrict__ Wk,
    const float* __restrict__ Wv,
    bf16_t* __restrict__ xb, bf16_t* __restrict__ WtAll)
{
  __shared__ float Ls[64][65];
  const int wg = blockIdx.x;
  const int tid = threadIdx.x;
  if (wg < 4096) {
    size_t i = ((size_t)wg * 256 + tid) * 8;
    float4 a = *(const float4*)(x + i);
    float4 b = *(const float4*)(x + i + 4);
    bf16x8 v;
    v[0] = (bf16_t)a.x; v[1] = (bf16_t)a.y; v[2] = (bf16_t)a.z; v[3] = (bf16_t)a.w;
    v[4] = (bf16_t)b.x; v[5] = (bf16_t)b.y; v[6] = (bf16_t)b.z; v[7] = (bf16_t)b.w;
    *(bf16x8*)(xb + i) = v;
    return;
  }
  const int r_ = wg - 4096;              // 0..767
  const int z = r_ >> 8;                 // 0..2
  const int rem = r_ & 255;              // 16 x 16
  const float* W = (z == 0) ? Wq : (z == 1) ? Wk : Wv;
  bf16_t* Wt = WtAll + (size_t)z * 1024 * D_;
  const int k0 = (rem >> 4) * 64, n0 = (rem & 15) * 64;
  const int rr = tid >> 4, cc = (tid & 15) * 4;
#pragma unroll
  for (int it = 0; it < 4; ++it) {
    int r = rr + it * 16;
    float4 v = *(const float4*)(W + (size_t)(k0 + r) * D_ + n0 + cc);
    Ls[r][cc] = v.x; Ls[r][cc + 1] = v.y; Ls[r][cc + 2] = v.z; Ls[r][cc + 3] = v.w;
  }
  __syncthreads();
#pragma unroll
  for (int it = 0; it < 4; ++it) {
    int nl = rr + it * 16;
    bf16x4 o;
    o[0] = (bf16_t)Ls[cc][nl];     o[1] = (bf16_t)Ls[cc + 1][nl];
    o[2] = (bf16_t)Ls[cc + 2][nl]; o[3] = (bf16_t)Ls[cc + 3][nl];
    *(bf16x4*)(Wt + (size_t)(n0 + nl) * D_ + k0 + cc) = o;
  }
}

// ---------------------------------------------------------------------------
// fused QKV GEMM v2 (round-15, measured best): 256x128 tiles, 512 threads /
// 8 waves, BK=64, global_load_lds staging, mb-fastest XCD map. Grid 768.
// ---------------------------------------------------------------------------
__global__ __launch_bounds__(512) void gemm_qkv(
    const bf16_t* __restrict__ A, const bf16_t* __restrict__ Bt,
    const float* __restrict__ bq, const float* __restrict__ bk,
    const float* __restrict__ bv,
    bf16_t* __restrict__ Qo, bf16_t* __restrict__ Ko, bf16_t* __restrict__ Vo)
{
  __shared__ __align__(16) bf16_t As[256 * 64];   // 32 KB
  __shared__ __align__(16) bf16_t Bs[128 * 64];   // 16 KB
  const int tid = threadIdx.x, lane = tid & 63, wv = tid >> 6;
  const int wr = wv >> 1, wc = wv & 1;
  const int wg = blockIdx.x;
  const int xcd = wg & 7;
  const int local = wg >> 3;                    // 0..95
  const int mb = xcd * 4 + (local & 3);         // 32 mb, 4 per XCD
  const int nb = local >> 2;                    // 0..23
  const int m0 = mb * 256, n0 = nb * 128;
  const int mode = nb >> 3;                     // 0..2
  const int lr = lane & 15, lg = lane >> 4;
  const int srow = tid >> 3;                    // 0..63
  const int scol = (tid & 7) * 8;               // k elems

  f32x4 acc[4][4] = {};

  for (int k0 = 0; k0 < D_; k0 += 64) {
    __syncthreads();
#pragma unroll
    for (int i = 0; i < 4; ++i)
      gload_lds16(A + (size_t)(m0 + i * 64 + srow) * D_ + k0 + scol,
                  &As[(i * 64 + (wv << 3)) * 64]);
#pragma unroll
    for (int i = 0; i < 2; ++i)
      gload_lds16(Bt + (size_t)(n0 + i * 64 + srow) * D_ + k0 + scol,
                  &Bs[(i * 64 + (wv << 3)) * 64]);
    __syncthreads();

#pragma unroll
    for (int ks = 0; ks < 2; ++ks) {
      bf16x8 af[4], bfr[4];
#pragma unroll
      for (int i = 0; i < 4; ++i)
        af[i] = *(const bf16x8*)&As[(wr * 64 + i * 16 + lr) * 64 + ks * 32 + lg * 8];
#pragma unroll
      for (int j = 0; j < 4; ++j)
        bfr[j] = *(const bf16x8*)&Bs[(wc * 64 + j * 16 + lr) * 64 + ks * 32 + lg * 8];
#pragma unroll
      for (int i = 0; i < 4; ++i)
#pragma unroll
        for (int j = 0; j < 4; ++j)
          acc[i][j] = mfma16(af[i], bfr[j], acc[i][j]);
    }
  }

  bf16_t* out = (mode == 0) ? Qo : (mode == 1) ? Ko : Vo;
  const float* bias = (mode == 0) ? bq : (mode == 1) ? bk : bv;
  const float scale = (mode == 0) ? QSCALE : 1.0f;
  const int nl0 = n0 - mode * 1024;
#pragma unroll
  for (int j = 0; j < 4; ++j) {
    int n = nl0 + wc * 64 + j * 16 + lr;
    float bval = bias[n];
    int h = n >> 6, d = n & 63;
#pragma unroll
    for (int i = 0; i < 4; ++i)
#pragma unroll
      for (int r = 0; r < 4; ++r) {
        int m = m0 + wr * 64 + i * 16 + lg * 4 + r;
        int b = m >> 11, t = m & (T_ - 1);
        float val = (acc[i][j][r] + bval) * scale;
        out[(((size_t)(b * H_ + h)) * T_ + t) * HD_ + d] = (bf16_t)val;
      }
  }
}

// ---------------------------------------------------------------------------
// fallback GEMM (fp32 inputs) — natural output only
// ---------------------------------------------------------------------------
__global__ __launch_bounds__(256) void qkv_gemm_f32(
    const float* __restrict__ x, const float* __restrict__ W,
    const float* __restrict__ bias, bf16_t* __restrict__ out, float scale)
{
  __shared__ bf16_t As[128][40];
  __shared__ bf16_t Bs[128][40];
  const int tid = threadIdx.x, lane = tid & 63, wv = tid >> 6;
  const int wr = wv >> 1, wc = wv & 1;
  const int m0 = blockIdx.y * 128, n0 = blockIdx.x * 128;
  const int lr = lane & 15, lg = lane >> 4;
  f32x4 acc[4][4] = {};
  const int xr = tid >> 3, xc = tid & 7;
  const int wk = tid >> 5, wn = tid & 31;

  for (int k0 = 0; k0 < D_; k0 += 32) {
    __syncthreads();
#pragma unroll
    for (int it = 0; it < 4; ++it) {
      int r = xr + it * 32;
      float4 v = *(const float4*)(x + (size_t)(m0 + r) * D_ + k0 + xc * 4);
      bf16_t* dst = &As[r][xc * 4];
      dst[0] = (bf16_t)v.x; dst[1] = (bf16_t)v.y;
      dst[2] = (bf16_t)v.z; dst[3] = (bf16_t)v.w;
    }
#pragma unroll
    for (int it = 0; it < 4; ++it) {
      int k = wk + it * 8;
      float4 v = *(const float4*)(W + (size_t)(k0 + k) * D_ + n0 + wn * 4);
      Bs[wn * 4 + 0][k] = (bf16_t)v.x;
      Bs[wn * 4 + 1][k] = (bf16_t)v.y;
      Bs[wn * 4 + 2][k] = (bf16_t)v.z;
      Bs[wn * 4 + 3][k] = (bf16_t)v.w;
    }
    __syncthreads();
    bf16x8 af[4], bfr[4];
#pragma unroll
    for (int i = 0; i < 4; ++i) af[i]  = *(const bf16x8*)&As[wr * 64 + i * 16 + lr][lg * 8];
#pragma unroll
    for (int j = 0; j < 4; ++j) bfr[j] = *(const bf16x8*)&Bs[wc * 64 + j * 16 + lr][lg * 8];
#pragma unroll
    for (int i = 0; i < 4; ++i)
#pragma unroll
      for (int j = 0; j < 4; ++j)
        acc[i][j] = mfma16(af[i], bfr[j], acc[i][j]);
  }

#pragma unroll
  for (int j = 0; j < 4; ++j) {
    int n = n0 + wc * 64 + j * 16 + lr;
    float bval = bias[n];
    int h = n >> 6, d = n & 63;
#pragma unroll
    for (int i = 0; i < 4; ++i)
#pragma unroll
      for (int r = 0; r < 4; ++r) {
        int m = m0 + wr * 64 + i * 16 + lg * 4 + r;
        int b = m >> 11, t = m & (T_ - 1);
        float val = (acc[i][j][r] + bval) * scale;
        out[(((size_t)(b * H_ + h)) * T_ + t) * HD_ + d] = (bf16_t)val;
      }
  }
}

// ---------------------------------------------------------------------------
// attn_rowsum (round-15, measured best): Lsum[bh,q] += sum_t 2^s. Wave holds
// 64 q as A-frags; streams K two 16-row groups per iteration. 1024 blocks =
// 8 xcd * 8 bh * 8 qc * 2 th. No LDS, no barriers.
// ---------------------------------------------------------------------------
__global__ __launch_bounds__(256) void attn_rowsum(
    const bf16_t* __restrict__ Q, const bf16_t* __restrict__ K,
    float* __restrict__ Lsum)
{
  const int tid = threadIdx.x, lane = tid & 63, wv = tid >> 6;
  const int lr = lane & 15, lg = lane >> 4;
  const int wg = blockIdx.x;
  const int p_ = wg >> 3;
  const int bh = (wg & 7) * 8 + (p_ >> 4);
  const int rem = p_ & 15;
  const int qc = rem >> 1;
  const int th = rem & 1;
  const int q0w = qc * 256 + wv * 64;

  const bf16_t* Qb = Q + (size_t)bh * T_ * HD_;
  const bf16_t* Kb = K + (size_t)bh * T_ * HD_;

  bf16x8 qa[4][2];
#pragma unroll
  for (int qq = 0; qq < 4; ++qq)
#pragma unroll
    for (int ks = 0; ks < 2; ++ks)
      qa[qq][ks] = *(const bf16x8*)(Qb + (size_t)(q0w + qq * 16 + lr) * HD_ +
                                    ks * 32 + lg * 8);

  float acc[4][4] = {};   // [qq][r] : q = q0w + qq*16 + 4*lg + r

  const int tlo = th * (T_ / 2), thi = tlo + T_ / 2;
  for (int tb = tlo; tb < thi; tb += 64) {
#pragma unroll
    for (int ts = 0; ts < 2; ++ts) {
      const int tA = tb + ts * 32 + lr;
      const int tB = tA + 16;
      bf16x8 kA0 = *(const bf16x8*)(Kb + (size_t)tA * HD_ + lg * 8);
      bf16x8 kA1 = *(const bf16x8*)(Kb + (size_t)tA * HD_ + 32 + lg * 8);
      bf16x8 kB0 = *(const bf16x8*)(Kb + (size_t)tB * HD_ + lg * 8);
      bf16x8 kB1 = *(const bf16x8*)(Kb + (size_t)tB * HD_ + 32 + lg * 8);
#pragma unroll
      for (int qq = 0; qq < 4; ++qq) {
        f32x4 sA = {}, sB = {};
        __builtin_amdgcn_s_setprio(1);
        sA = mfma16(qa[qq][0], kA0, sA);
        sA = mfma16(qa[qq][1], kA1, sA);
        sB = mfma16(qa[qq][0], kB0, sB);
        sB = mfma16(qa[qq][1], kB1, sB);
        __builtin_amdgcn_s_setprio(0);
#pragma unroll
        for (int r = 0; r < 4; ++r)
          acc[qq][r] += exp2g(sA[r]) + exp2g(sB[r]);
      }
    }
  }

#pragma unroll
  for (int qq = 0; qq < 4; ++qq)
#pragma unroll
    for (int r = 0; r < 4; ++r) {
      float v = acc[qq][r];
      v += __shfl_xor(v, 1); v += __shfl_xor(v, 2);
      v += __shfl_xor(v, 4); v += __shfl_xor(v, 8);
      acc[qq][r] = v;
    }
  if (lr == 0) {
#pragma unroll
    for (int qq = 0; qq < 4; ++qq)
#pragma unroll
      for (int r = 0; r < 4; ++r)
        atomicAdd(&Lsum[(size_t)bh * T_ + q0w + qq * 16 + lg * 4 + r],
                  acc[qq][r]);
  }
}

// ---------------------------------------------------------------------------
// attn_colsum (round-15): colsum[b,t] += sum_q 2^s / Lsum[q] (rcp folded).
// Wave holds 128 t; streams Q two 16-row groups per iteration. 1024 blocks.
// ---------------------------------------------------------------------------
__global__ __launch_bounds__(256) void attn_colsum(
    const bf16_t* __restrict__ Q, const bf16_t* __restrict__ K,
    const float* __restrict__ Lsum, float* __restrict__ colsum)
{
  const int tid = threadIdx.x, lane = tid & 63, wv = tid >> 6;
  const int lr = lane & 15, lg = lane >> 4;
  const int wg = blockIdx.x;
  const int p_ = wg >> 3;
  const int bh = (wg & 7) * 8 + (p_ >> 4);
  const int rem = p_ & 15;
  const int tc = rem >> 2;
  const int qs = rem & 3;
  const int b = bh >> 4;
  const int t0w = tc * 512 + wv * 128;

  const bf16_t* Qb = Q + (size_t)bh * T_ * HD_;
  const bf16_t* Kb = K + (size_t)bh * T_ * HD_;
  const float* Lb = Lsum + (size_t)bh * T_;

  bf16x8 kf[8][2];
#pragma unroll
  for (int tt = 0; tt < 8; ++tt)
#pragma unroll
    for (int ks = 0; ks < 2; ++ks)
      kf[tt][ks] = *(const bf16x8*)(Kb + (size_t)(t0w + tt * 16 + lr) * HD_ +
                                    ks * 32 + lg * 8);

  float acc[8][4] = {};   // [tt][r] : t = t0w + tt*16 + 4*lg + r

  const int qlo = qs * (T_ / 4), qhi = qlo + T_ / 4;
  for (int qb = qlo; qb < qhi; qb += 64) {
#pragma unroll
    for (int qp = 0; qp < 2; ++qp) {
      const int qA = qb + qp * 32 + lr;
      const int qB = qA + 16;
      bf16x8 qA0 = *(const bf16x8*)(Qb + (size_t)qA * HD_ + lg * 8);
      bf16x8 qA1 = *(const bf16x8*)(Qb + (size_t)qA * HD_ + 32 + lg * 8);
      bf16x8 qB0 = *(const bf16x8*)(Qb + (size_t)qB * HD_ + lg * 8);
      bf16x8 qB1 = *(const bf16x8*)(Qb + (size_t)qB * HD_ + 32 + lg * 8);
      const float lvA = rcpg(Lb[qA]);
      const float lvB = rcpg(Lb[qB]);
#pragma unroll
      for (int tt = 0; tt < 8; ++tt) {
        f32x4 sA = {}, sB = {};
        __builtin_amdgcn_s_setprio(1);
        sA = mfma16(kf[tt][0], qA0, sA);
        sA = mfma16(kf[tt][1], qA1, sA);
        sB = mfma16(kf[tt][0], qB0, sB);
        sB = mfma16(kf[tt][1], qB1, sB);
        __builtin_amdgcn_s_setprio(0);
#pragma unroll
        for (int r = 0; r < 4; ++r) {
          acc[tt][r] = fmaf(exp2g(sA[r]), lvA, acc[tt][r]);
          acc[tt][r] = fmaf(exp2g(sB[r]), lvB, acc[tt][r]);
        }
      }
    }
  }

#pragma unroll
  for (int tt = 0; tt < 8; ++tt)
#pragma unroll
    for (int r = 0; r < 4; ++r) {
      float v = acc[tt][r];
      v += __shfl_xor(v, 1); v += __shfl_xor(v, 2);
      v += __shfl_xor(v, 4); v += __shfl_xor(v, 8);
      acc[tt][r] = v;
    }
  if (lr == 0) {
#pragma unroll
    for (int tt = 0; tt < 8; ++tt)
#pragma unroll
      for (int r = 0; r < 4; ++r)
        atomicAdd(&colsum[b * T_ + t0w + tt * 16 + lg * 4 + r], acc[tt][r]);
  }
}

// ---------------------------------------------------------------------------
// attn_w2 (round-15): w2[bh,k] += sum_t (colsum[b,t]/32768) * 2^s / Lsum[t].
// ---------------------------------------------------------------------------
__global__ __launch_bounds__(256) void attn_w2(
    const bf16_t* __restrict__ Q, const bf16_t* __restrict__ K,
    const float* __restrict__ Lsum, const float* __restrict__ CS,
    float* __restrict__ w2)
{
  const int tid = threadIdx.x, lane = tid & 63, wv = tid >> 6;
  const int lr = lane & 15, lg = lane >> 4;
  const int wg = blockIdx.x;
  const int p_ = wg >> 3;
  const int bh = (wg & 7) * 8 + (p_ >> 4);
  const int rem = p_ & 15;
  const int tc = rem >> 2;
  const int qs = rem & 3;
  const int b = bh >> 4;
  const int t0w = tc * 512 + wv * 128;

  const bf16_t* Qb = Q + (size_t)bh * T_ * HD_;
  const bf16_t* Kb = K + (size_t)bh * T_ * HD_;
  const float* Lb = Lsum + (size_t)bh * T_;
  const float* Cb = CS + (size_t)b * T_;

  bf16x8 kf[8][2];
#pragma unroll
  for (int tt = 0; tt < 8; ++tt)
#pragma unroll
    for (int ks = 0; ks < 2; ++ks)
      kf[tt][ks] = *(const bf16x8*)(Kb + (size_t)(t0w + tt * 16 + lr) * HD_ +
                                    ks * 32 + lg * 8);

  float acc[8][4] = {};

  const int qlo = qs * (T_ / 4), qhi = qlo + T_ / 4;
  for (int qb = qlo; qb < qhi; qb += 64) {
#pragma unroll
    for (int qp = 0; qp < 2; ++qp) {
      const int qA = qb + qp * 32 + lr;
      const int qB = qA + 16;
      bf16x8 qA0 = *(const bf16x8*)(Qb + (size_t)qA * HD_ + lg * 8);
      bf16x8 qA1 = *(const bf16x8*)(Qb + (size_t)qA * HD_ + 32 + lg * 8);
      bf16x8 qB0 = *(const bf16x8*)(Qb + (size_t)qB * HD_ + lg * 8);
      bf16x8 qB1 = *(const bf16x8*)(Qb + (size_t)qB * HD_ + 32 + lg * 8);
      const float lvA = Cb[qA] * rcpg(Lb[qA]) * (1.f / 32768.f);
      const float lvB = Cb[qB] * rcpg(Lb[qB]) * (1.f / 32768.f);
#pragma unroll
      for (int tt = 0; tt < 8; ++tt) {
        f32x4 sA = {}, sB = {};
        __builtin_amdgcn_s_setprio(1);
        sA = mfma16(kf[tt][0], qA0, sA);
        sA = mfma16(kf[tt][1], qA1, sA);
        sB = mfma16(kf[tt][0], qB0, sB);
        sB = mfma16(kf[tt][1], qB1, sB);
        __builtin_amdgcn_s_setprio(0);
#pragma unroll
        for (int r = 0; r < 4; ++r) {
          acc[tt][r] = fmaf(exp2g(sA[r]), lvA, acc[tt][r]);
          acc[tt][r] = fmaf(exp2g(sB[r]), lvB, acc[tt][r]);
        }
      }
    }
  }

#pragma unroll
  for (int tt = 0; tt < 8; ++tt)
#pragma unroll
    for (int r = 0; r < 4; ++r) {
      float v = acc[tt][r];
      v += __shfl_xor(v, 1); v += __shfl_xor(v, 2);
      v += __shfl_xor(v, 4); v += __shfl_xor(v, 8);
      acc[tt][r] = v;
    }
  if (lr == 0) {
#pragma unroll
    for (int tt = 0; tt < 8; ++tt)
#pragma unroll
      for (int r = 0; r < 4; ++r)
        atomicAdd(&w2[(size_t)bh * T_ + t0w + tt * 16 + lg * 4 + r],
                  acc[tt][r]);
  }
}

// ---------------------------------------------------------------------------
// pool_wv: pre[b, h*64+d] += sum_{s in chunk} w2[bh,s] * V[bh,s,d]
// ---------------------------------------------------------------------------
__global__ __launch_bounds__(256) void pool_wv(
    const bf16_t* __restrict__ V, const float* __restrict__ W2,
    float* __restrict__ pre)
{
  __shared__ float sm[256];
  const int wg = blockIdx.x;
  const int bh = wg >> 3, sc = wg & 7;
  const int b = bh >> 4, h = bh & 15;
  const int tid = threadIdx.x, d = tid & 63, tg = tid >> 6;
  const bf16_t* Vb = V + (size_t)bh * T_ * HD_ + (size_t)sc * 256 * HD_;
  const float* wb = W2 + (size_t)bh * T_ + sc * 256;
  float acc = 0.f;
  for (int s = tg; s < 256; s += 4)
    acc += wb[s] * (float)Vb[(size_t)s * HD_ + d];
  sm[tid] = acc;
  __syncthreads();
  if (tid < 64) {
    float s = sm[tid] + sm[tid + 64] + sm[tid + 128] + sm[tid + 192];
    atomicAdd(&pre[b * D_ + h * 64 + tid], s);
  }
}

// ---------------------------------------------------------------------------
// out_acc: out[b,d] += sum_{k in chunk} pre[b,k]*Wo[k,d]  (+bo[d] on chunk 0)
// ---------------------------------------------------------------------------
__global__ __launch_bounds__(256) void out_acc(
    const float* __restrict__ pre, const float* __restrict__ Wo,
    const float* __restrict__ bo, float* __restrict__ out)
{
  const int dc = blockIdx.x & 3, kb = blockIdx.x >> 2;
  const int d = dc * 256 + threadIdx.x;
  const int k0 = kb * 32;
  float acc0 = 0.f, acc1 = 0.f, acc2 = 0.f, acc3 = 0.f;
#pragma unroll
  for (int kk = 0; kk < 32; ++kk) {
    const int k = k0 + kk;
    const float w = Wo[(size_t)k * D_ + d];
    acc0 = fmaf(pre[k],            w, acc0);
    acc1 = fmaf(pre[D_ + k],       w, acc1);
    acc2 = fmaf(pre[2 * D_ + k],   w, acc2);
    acc3 = fmaf(pre[3 * D_ + k],   w, acc3);
  }
  if (kb == 0) {
    const float bd = bo[d];
    acc0 += bd; acc1 += bd; acc2 += bd; acc3 += bd;
  }
  atomicAdd(&out[d],           acc0);
  atomicAdd(&out[D_ + d],      acc1);
  atomicAdd(&out[2 * D_ + d],  acc2);
  atomicAdd(&out[3 * D_ + d],  acc3);
}

// ---------------------------------------------------------------------------
extern "C" void kernel_launch(void* const* d_in, const int* in_sizes, int n_in,
                              void* d_out, int out_size, void* d_ws, size_t ws_size,
                              hipStream_t stream)
{
  (void)in_sizes; (void)n_in; (void)out_size;
  const float* x  = (const float*)d_in[0];
  const float* Wq = (const float*)d_in[1];
  const float* bq = (const float*)d_in[2];
  const float* Wk = (const float*)d_in[3];
  const float* bk = (const float*)d_in[4];
  const float* Wv = (const float*)d_in[5];
  const float* bv = (const float*)d_in[6];
  const float* Wo = (const float*)d_in[7];
  const float* bo = (const float*)d_in[8];
  float* out = (float*)d_out;

  char* ws = (char*)d_ws;
  const size_t MB = 1ull << 20;
  const size_t KB = 1024;
  bf16_t* Qw = (bf16_t*)(ws);
  bf16_t* Kw = (bf16_t*)(ws + 16 * MB);
  bf16_t* Vw = (bf16_t*)(ws + 32 * MB);
  bf16_t* XB = (bf16_t*)(ws + 48 * MB);
  const size_t need_fast = 72 * MB;
  const bool fast = ws_size >= need_fast;

  // scalars region (all zeroed in one memset): LV | CS | PRE | W2
  size_t soff = fast ? 70 * MB : 64 * MB;
  float* LV  = (float*)(ws + soff);                    // 512 KB (Lsum)
  float* CS  = (float*)(ws + soff + 512 * KB);         // 32 KB
  float* PRE = (float*)(ws + soff + 544 * KB);         // 16 KB
  float* W2  = (float*)(ws + soff + 560 * KB);         // 512 KB
  dim3 blk(256, 1, 1);

  if (fast) {
    bf16_t* WtAll = (bf16_t*)(ws + 64 * MB);  // [3072][1024] bf16 = 6 MB
    conv_all<<<dim3(4864, 1, 1), blk, 0, stream>>>(x, Wq, Wk, Wv, XB, WtAll);
    gemm_qkv<<<dim3(768, 1, 1), dim3(512, 1, 1), 0, stream>>>(
        XB, WtAll, bq, bk, bv, Qw, Kw, Vw);
  } else {
    qkv_gemm_f32<<<dim3(8, 64, 1), blk, 0, stream>>>(x, Wq, bq, Qw, QSCALE);
    qkv_gemm_f32<<<dim3(8, 64, 1), blk, 0, stream>>>(x, Wk, bk, Kw, 1.0f);
    qkv_gemm_f32<<<dim3(8, 64, 1), blk, 0, stream>>>(x, Wv, bv, Vw, 1.0f);
  }

  hipMemsetAsync(LV, 0, 1072 * KB, stream);
  hipMemsetAsync(out, 0, (size_t)B_ * D_ * sizeof(float), stream);

  attn_rowsum<<<dim3(1024, 1, 1), blk, 0, stream>>>(Qw, Kw, LV);
  attn_colsum<<<dim3(1024, 1, 1), blk, 0, stream>>>(Qw, Kw, LV, CS);
  attn_w2<<<dim3(1024, 1, 1), blk, 0, stream>>>(Qw, Kw, LV, CS, W2);
  pool_wv<<<dim3(512, 1, 1), blk, 0, stream>>>(Vw, W2, PRE);
  out_acc<<<dim3(128, 1, 1), blk, 0, stream>>>(PRE, Wo, bo, out);
}